// Round 12
// baseline (196.805 us; speedup 1.0000x reference)
//
#include <hip/hip_runtime.h>
#include <hip/hip_bf16.h>

typedef _Float16 half8 __attribute__((ext_vector_type(8)));
typedef _Float16 half4v __attribute__((ext_vector_type(4)));
typedef _Float16 half2 __attribute__((ext_vector_type(2)));
typedef float f32x4 __attribute__((ext_vector_type(4)));

constexpr int NT = 4096;   // tokens
constexpr int CH = 1024;   // channels
constexpr int NH = 16;     // heads
constexpr int HD = 64;     // head dim
constexpr int C3 = 3072;   // 3*CH

#if __has_builtin(__builtin_amdgcn_exp2f)
#define EXP2(x) __builtin_amdgcn_exp2f(x)
#else
#define EXP2(x) exp2f(x)
#endif

#define GLOAD_LDS16(gp, lp) __builtin_amdgcn_global_load_lds( \
    (const __attribute__((address_space(1))) void*)(gp),      \
    (__attribute__((address_space(3))) void*)(lp), 16, 0, 0)

static __device__ inline half2 pk_f16(float a, float b) {
  auto r = __builtin_amdgcn_cvt_pkrtz(a, b);   // v_cvt_pkrtz_f16_f32
  return *(half2*)&r;
}

// ---------------- fused f32 -> f16 convert (x, w_qkv, w_out in one launch) ----------------
__global__ __launch_bounds__(256) void cvt3_kernel(const float* __restrict__ a, int na4,
                                                   const float* __restrict__ b, int nb4,
                                                   const float* __restrict__ c, int nc4,
                                                   _Float16* __restrict__ oa,
                                                   _Float16* __restrict__ ob,
                                                   _Float16* __restrict__ oc) {
  int i = blockIdx.x * 256 + threadIdx.x;
  const float* src; _Float16* dst; int j = i;
  if (i < na4) { src = a; dst = oa; }
  else if (i < na4 + nb4) { src = b; dst = ob; j = i - na4; }
  else if (i < na4 + nb4 + nc4) { src = c; dst = oc; j = i - na4 - nb4; }
  else return;
  float4 v = ((const float4*)src)[j];
  half4v h;
  h[0] = (_Float16)v.x; h[1] = (_Float16)v.y; h[2] = (_Float16)v.z; h[3] = (_Float16)v.w;
  ((half4v*)dst)[j] = h;
}

// ---------------- GEMM: C[M][Nn] = A[M][K] * Bt[Nn][K]^T ----------------
// 128x128 tile, BK=32, linear LDS, global_load_lds width-16 staging.
// 2-phase double-buffer; 1D grid with bijective XCD swizzle (nwg % 8 == 0):
// consecutive post-swizzle blocks share a B panel within one XCD's L2 (T1).
template <typename OutT>
__global__ __launch_bounds__(256) void gemm_bt(const _Float16* __restrict__ A,
                                               const _Float16* __restrict__ Bt,
                                               OutT* __restrict__ Cc,
                                               int M, int Nn, int K, int nbx) {
  __shared__ _Float16 As[2][128][32];
  __shared__ _Float16 Bs[2][128][32];
  const int tid = threadIdx.x;
  const int lane = tid & 63, w = tid >> 6;
  const int l15 = lane & 15, l4 = lane >> 4;
  int nwg = gridDim.x, cpx = nwg >> 3;
  int wg = (blockIdx.x & 7) * cpx + (blockIdx.x >> 3);
  const int m0 = (wg % nbx) * 128, n0 = (wg / nbx) * 128;
  const int wr = w >> 1, wc = w & 1;
  const int rb = w * 32;           // wave's 32-row staging band
  const int rl = lane >> 2;        // row within 16-row chunk (4 lanes/row)
  const int cb = (lane & 3) * 8;   // f16 col of this lane's 16B
  f32x4 acc[4][4] = {};
  auto stage = [&](int k0, int buf) {
    GLOAD_LDS16(A  + (size_t)(m0 + rb + rl) * K + k0 + cb,      &As[buf][rb][0]);
    GLOAD_LDS16(A  + (size_t)(m0 + rb + 16 + rl) * K + k0 + cb, &As[buf][rb + 16][0]);
    GLOAD_LDS16(Bt + (size_t)(n0 + rb + rl) * K + k0 + cb,      &Bs[buf][rb][0]);
    GLOAD_LDS16(Bt + (size_t)(n0 + rb + 16 + rl) * K + k0 + cb, &Bs[buf][rb + 16][0]);
  };
  auto compute = [&](int buf) {
    half8 af[4], bf[4];
#pragma unroll
    for (int mt = 0; mt < 4; ++mt) af[mt] = *(half8*)&As[buf][wr * 64 + mt * 16 + l15][l4 * 8];
#pragma unroll
    for (int nt = 0; nt < 4; ++nt) bf[nt] = *(half8*)&Bs[buf][wc * 64 + nt * 16 + l15][l4 * 8];
#pragma unroll
    for (int mt = 0; mt < 4; ++mt)
#pragma unroll
      for (int nt = 0; nt < 4; ++nt)
        acc[mt][nt] = __builtin_amdgcn_mfma_f32_16x16x32_f16(af[mt], bf[nt], acc[mt][nt], 0, 0, 0);
  };
  stage(0, 0);
  __syncthreads();                 // tile 0 staged (vmcnt drain at barrier)
  for (int k0 = 0; k0 < K; k0 += 64) {
    stage(k0 + 32, 1);             // in flight during compute(0); k0+32 < K
    compute(0);
    __syncthreads();               // buf1 writes drained; buf0 readers done
    if (k0 + 64 < K) stage(k0 + 64, 0);
    compute(1);
    __syncthreads();
  }
#pragma unroll
  for (int mt = 0; mt < 4; ++mt)
#pragma unroll
    for (int nt = 0; nt < 4; ++nt)
#pragma unroll
      for (int r = 0; r < 4; ++r) {
        int row = m0 + wr * 64 + mt * 16 + l4 * 4 + r;
        int col = n0 + wc * 64 + nt * 16 + l15;
        Cc[(size_t)row * Nn + col] = (OutT)acc[mt][nt][r];
      }
}

// ---------------- fused RMSNorm + RoPE for Q,K ----------------
// one wave per (n, h); lane = d. Q row-major pre-scaled by 0.125*log2(e).
// K written into fragment-swizzled KF layout (see attn_kernel header).
__global__ __launch_bounds__(256) void rmsrope_kernel(const _Float16* __restrict__ qkv,
                                                      const int* __restrict__ coords,
                                                      const float* __restrict__ gq,
                                                      const float* __restrict__ gk,
                                                      _Float16* __restrict__ Qh,
                                                      _Float16* __restrict__ KF) {
  int gw = blockIdx.x * 4 + (threadIdx.x >> 6);
  int lane = threadIdx.x & 63;
  int n = gw >> 4, h = gw & 15;
  float q = (float)qkv[(size_t)n * C3 + h * HD + lane];
  float k = (float)qkv[(size_t)n * C3 + CH + h * HD + lane];
  float sq = q * q, sk = k * k;
#pragma unroll
  for (int m = 1; m < 64; m <<= 1) { sq += __shfl_xor(sq, m); sk += __shfl_xor(sk, m); }
  q *= 8.0f / fmaxf(sqrtf(sq), 1e-12f) * gq[h * HD + lane];
  k *= 8.0f / fmaxf(sqrtf(sk), 1e-12f) * gk[h * HD + lane];
  int j = lane >> 1, p = j >> 3, dr = j & 7;
  // freq = 10000^(-dr/64) = exp(-dr * ln(1e4)/64)
  float ang = (float)coords[n * 5 + 1 + p] * __expf(-(float)dr * 0.14391157f);
  float cs = cosf(ang), sn = sinf(ang);
  float qp = __shfl_xor(q, 1), kp = __shfl_xor(k, 1);
  float qr, kr;
  if ((lane & 1) == 0) { qr = q * cs - qp * sn; kr = k * cs - kp * sn; }
  else                 { qr = qp * sn + q * cs; kr = kp * sn + k * cs; }
  Qh[((size_t)h * NT + n) * HD + lane] = (_Float16)(qr * 0.18033688f);  // 0.125*log2e
  // KF fragment-swizzle: key m=n&63 -> (t, i15); d=lane -> (kk, l4, j)
  int m64 = n & 63, kb = n >> 6;
  int t   = 2 * (m64 >> 5) + ((m64 >> 2) & 1);
  int i15 = 4 * ((m64 >> 3) & 3) + (m64 & 3);
  int kk = lane >> 5, ll4 = (lane >> 3) & 3, jj = lane & 7;
  KF[(size_t)h * NT * HD + (size_t)kb * 4096 +
     (size_t)(((t * 2 + kk) * 64 + ll4 * 16 + i15) * 8 + jj)] = (_Float16)kr;
}

// ---------------- V into fragment-swizzled VF layout ----------------
// VF element (kb, f=t*2+kk, lane=l4*16+l15, j) = V[key=kb*64+kk*32+l4*8+j][d=t*16+l15]
__global__ __launch_bounds__(256) void vtrans_kernel(const _Float16* __restrict__ qkv,
                                                     _Float16* __restrict__ VF) {
  __shared__ _Float16 L[64][72];
  int h = blockIdx.y, n0 = blockIdx.x * 64, kb = blockIdx.x, t0 = threadIdx.x;
#pragma unroll
  for (int i = 0; i < 2; ++i) {
    int cid = t0 + i * 256, r = cid >> 3, c = cid & 7;
    *(half8*)&L[r][c * 8] = *(const half8*)(qkv + (size_t)(n0 + r) * C3 + 2 * CH + h * HD + c * 8);
  }
  __syncthreads();
#pragma unroll
  for (int i = 0; i < 2; ++i) {
    int cid = t0 + i * 256, d = cid >> 3, c = cid & 7;
    half8 v;
#pragma unroll
    for (int jj = 0; jj < 8; ++jj) v[jj] = L[c * 8 + jj][d];
    size_t flat = (size_t)h * NT * HD + (size_t)kb * 4096 +
                  (size_t)((((d >> 4) * 2 + (c >> 2)) * 64 + (c & 3) * 16 + (d & 15)) * 8);
    *(half8*)(VF + flat) = v;
  }
}

// ---------------- flash attention: qb=4, 2 waves/block, 2-phase gload_lds ----------------
// one block = (head, 128-row Q tile); 2 waves x 64 q-rows; grid 512 (2 blocks/CU,
// 1 wave/SIMD). Rationale: LDS-read traffic scales with waves/CU x K/V bytes;
// qb=4 halves it (41 -> 20.5 us/CU) making MFMA the max pipe. Large per-tile
// ILP pools (32 indep qk MFMAs, 64 exps, 40 pv MFMAs) cover latency in-wave.
// Bounded scores (|S|<=8) -> no max tracking. Swapped QK^T -> P in registers.
// lsum via MFMA ones-frag. Zero staging VALU / registers (gload_lds).
__global__ __launch_bounds__(128, 1) void attn_kernel(const _Float16* __restrict__ Qh,
                                                      const _Float16* __restrict__ KF,
                                                      const _Float16* __restrict__ VF,
                                                      _Float16* __restrict__ Oh) {
  __shared__ _Float16 KB[2][4096];
  __shared__ _Float16 VB[2][4096];
  const int tid = threadIdx.x, lane = tid & 63, w = tid >> 6;   // w in {0,1}
  const int l15 = lane & 15, l4 = lane >> 4;
  // XCD-aware mapping: 512 blocks, heads {2x,2x+1} pinned to XCD x
  int bid = blockIdx.x;
  int s = bid >> 3;                 // [0,64)
  int h = (bid & 7) * 2 + (s >> 5);
  int n0 = (s & 31) * 128;
  half8 qf[4][2];  // [qb][kk], q rows = n0 + w*64 + qb*16 + l15
#pragma unroll
  for (int qb = 0; qb < 4; ++qb)
#pragma unroll
    for (int kk = 0; kk < 2; ++kk)
      qf[qb][kk] = *(const half8*)(Qh + ((size_t)h * NT + n0 + w * 64 + qb * 16 + l15) * HD + kk * 32 + l4 * 8);
  f32x4 acc[4][4] = {};
  f32x4 acc5[4] = {};              // lsum accumulators (col 0 = row-sum)
  half8 of1 = {};                  // ones B-frag: B[idx=0][k]=1 -> l15==0 lanes
  if (l15 == 0) {
#pragma unroll
    for (int jq = 0; jq < 8; ++jq) of1[jq] = (_Float16)1.0f;
  }
  const _Float16* KFh = KF + (size_t)h * NT * HD + w * 2048 + lane * 8;
  const _Float16* VFh = VF + (size_t)h * NT * HD + w * 2048 + lane * 8;
  union U { half8 v; half2 p[4]; };
  auto stage = [&](int kb, int buf) {    // 8 gloads/wave: wave w covers halfs [w*2048, w*2048+2048)
    size_t g0 = (size_t)kb * 4096;
#pragma unroll
    for (int g = 0; g < 4; ++g) {
      GLOAD_LDS16(KFh + g0 + g * 512, &KB[buf][w * 2048 + g * 512]);
      GLOAD_LDS16(VFh + g0 + g * 512, &VB[buf][w * 2048 + g * 512]);
    }
  };
  auto compute = [&](int buf) {
    // QK^T (swapped): sv[qb][t], q = l15
    f32x4 sv[4][4] = {};
    __builtin_amdgcn_s_setprio(1);
#pragma unroll
    for (int t = 0; t < 4; ++t)
#pragma unroll
      for (int kk = 0; kk < 2; ++kk) {
        half8 kf = *(half8*)&KB[buf][(t * 2 + kk) * 512 + lane * 8];
#pragma unroll
        for (int qb = 0; qb < 4; ++qb)
          sv[qb][t] = __builtin_amdgcn_mfma_f32_16x16x32_f16(kf, qf[qb][kk], sv[qb][t], 0, 0, 0);
      }
    __builtin_amdgcn_s_setprio(0);
    // p = 2^S; pack with v_cvt_pkrtz. pf[kk][j] = e[2kk + (j>>2)][j&3]
    U u[4][2];
#pragma unroll
    for (int qb = 0; qb < 4; ++qb) {
      float e[4][4];
#pragma unroll
      for (int t = 0; t < 4; ++t)
#pragma unroll
        for (int r = 0; r < 4; ++r) e[t][r] = EXP2(sv[qb][t][r]);
      u[qb][0].p[0] = pk_f16(e[0][0], e[0][1]); u[qb][0].p[1] = pk_f16(e[0][2], e[0][3]);
      u[qb][0].p[2] = pk_f16(e[1][0], e[1][1]); u[qb][0].p[3] = pk_f16(e[1][2], e[1][3]);
      u[qb][1].p[0] = pk_f16(e[2][0], e[2][1]); u[qb][1].p[1] = pk_f16(e[2][2], e[2][3]);
      u[qb][1].p[2] = pk_f16(e[3][0], e[3][1]); u[qb][1].p[3] = pk_f16(e[3][2], e[3][3]);
    }
    // O += P @ V ; lsum via ones-frag (no LDS traffic)
    __builtin_amdgcn_s_setprio(1);
#pragma unroll
    for (int t = 0; t < 4; ++t)
#pragma unroll
      for (int kk = 0; kk < 2; ++kk) {
        half8 vf = *(half8*)&VB[buf][(t * 2 + kk) * 512 + lane * 8];
#pragma unroll
        for (int qb = 0; qb < 4; ++qb)
          acc[qb][t] = __builtin_amdgcn_mfma_f32_16x16x32_f16(u[qb][kk].v, vf, acc[qb][t], 0, 0, 0);
      }
#pragma unroll
    for (int qb = 0; qb < 4; ++qb) {
      acc5[qb] = __builtin_amdgcn_mfma_f32_16x16x32_f16(u[qb][0].v, of1, acc5[qb], 0, 0, 0);
      acc5[qb] = __builtin_amdgcn_mfma_f32_16x16x32_f16(u[qb][1].v, of1, acc5[qb], 0, 0, 0);
    }
    __builtin_amdgcn_s_setprio(0);
  };
  stage(0, 0);
  __syncthreads();                 // tile 0 staged (vmcnt drain at barrier)
  for (int kb = 0; kb < 64; kb += 2) {
    stage(kb + 1, 1);              // kb+1 <= 63, always valid
    compute(0);                    // tile kb
    __syncthreads();               // buf1 writes drained; buf0 readers done
    if (kb + 2 < 64) stage(kb + 2, 0);
    compute(1);                    // tile kb+1
    __syncthreads();
  }
  // lsum for q-row (qb*16 + l4*4+r) sits in acc5[qb][r] of lane (l4, l15=0)
#pragma unroll
  for (int qb = 0; qb < 4; ++qb) {
    float linv[4];
#pragma unroll
    for (int r = 0; r < 4; ++r) linv[r] = 1.0f / __shfl(acc5[qb][r], lane & 48);
#pragma unroll
    for (int t = 0; t < 4; ++t)
#pragma unroll
      for (int r = 0; r < 4; ++r) {
        int row = n0 + w * 64 + qb * 16 + l4 * 4 + r;
        Oh[(size_t)row * CH + h * HD + t * 16 + l15] = (_Float16)(acc[qb][t][r] * linv[r]);
      }
  }
}

extern "C" void kernel_launch(void* const* d_in, const int* in_sizes, int n_in,
                              void* d_out, int out_size, void* d_ws, size_t ws_size,
                              hipStream_t stream) {
  const float* x      = (const float*)d_in[0];
  const int*   coords = (const int*)d_in[1];
  const float* w_qkv  = (const float*)d_in[2];
  const float* w_out  = (const float*)d_in[3];
  const float* gq     = (const float*)d_in[4];
  const float* gk     = (const float*)d_in[5];
  float* out = (float*)d_out;

  char* ws = (char*)d_ws;
  size_t off = 0;
  auto alloc = [&](size_t bytes) { char* p = ws + off; off += bytes; return p; };
  _Float16* xh   = (_Float16*)alloc((size_t)NT * CH * 2);  // x in f16
  _Float16* wqh  = (_Float16*)alloc((size_t)C3 * CH * 2);  // w_qkv f16
  _Float16* woh  = (_Float16*)alloc((size_t)CH * CH * 2);  // w_out f16
  _Float16* qkvh = (_Float16*)alloc((size_t)NT * C3 * 2);  // qkv f16
  _Float16* Qh   = (_Float16*)alloc((size_t)NT * CH * 2);  // [H][N][64], pre-scaled
  _Float16* KFh  = (_Float16*)alloc((size_t)NT * CH * 2);  // frag-swizzled K
  _Float16* VFh  = (_Float16*)alloc((size_t)NT * CH * 2);  // frag-swizzled V
  _Float16* Oh   = (_Float16*)alloc((size_t)NT * CH * 2);  // attn out [N][C]
  if (off > ws_size) return;  // workspace too small: fail cleanly

  int na4 = NT * CH / 4, nb4 = C3 * CH / 4, nc4 = CH * CH / 4;
  cvt3_kernel<<<(na4 + nb4 + nc4) / 256, 256, 0, stream>>>(x, na4, w_qkv, nb4, w_out, nc4,
                                                           xh, wqh, woh);
  gemm_bt<_Float16><<<(NT / 128) * (C3 / 128), 256, 0, stream>>>(xh, wqh, qkvh, NT, C3, CH, NT / 128);
  rmsrope_kernel<<<NT * NH / 4, 256, 0, stream>>>(qkvh, coords, gq, gk, Qh, KFh);
  vtrans_kernel<<<dim3(NT / 64, NH), 256, 0, stream>>>(qkvh, VFh);
  attn_kernel<<<NH * (NT / 128), 128, 0, stream>>>(Qh, KFh, VFh, Oh);
  gemm_bt<float><<<(NT / 128) * (CH / 128), 256, 0, stream>>>(Oh, woh, out, NT, CH, CH, NT / 128);
}

// Round 13
// 182.868 us; speedup vs baseline: 1.0762x; 1.0762x over previous
//
#include <hip/hip_runtime.h>
#include <hip/hip_bf16.h>

typedef _Float16 half8 __attribute__((ext_vector_type(8)));
typedef _Float16 half4v __attribute__((ext_vector_type(4)));
typedef _Float16 half2 __attribute__((ext_vector_type(2)));
typedef float f32x4 __attribute__((ext_vector_type(4)));

constexpr int NT = 4096;   // tokens
constexpr int CH = 1024;   // channels
constexpr int NH = 16;     // heads
constexpr int HD = 64;     // head dim
constexpr int C3 = 3072;   // 3*CH

#if __has_builtin(__builtin_amdgcn_exp2f)
#define EXP2(x) __builtin_amdgcn_exp2f(x)
#else
#define EXP2(x) exp2f(x)
#endif

#define GLOAD_LDS16(gp, lp) __builtin_amdgcn_global_load_lds( \
    (const __attribute__((address_space(1))) void*)(gp),      \
    (__attribute__((address_space(3))) void*)(lp), 16, 0, 0)

static __device__ inline half2 pk_f16(float a, float b) {
  auto r = __builtin_amdgcn_cvt_pkrtz(a, b);   // v_cvt_pkrtz_f16_f32
  return *(half2*)&r;
}

// ---------------- f32 -> f16 convert, row-major (w_out) ----------------
__global__ __launch_bounds__(256) void cvt_kernel(const float* __restrict__ in,
                                                  _Float16* __restrict__ out, int n4) {
  int i = blockIdx.x * 256 + threadIdx.x;
  if (i >= n4) return;
  float4 v = ((const float4*)in)[i];
  half4v h;
  h[0] = (_Float16)v.x; h[1] = (_Float16)v.y; h[2] = (_Float16)v.z; h[3] = (_Float16)v.w;
  ((half4v*)out)[i] = h;
}

// ---------------- f32 -> f16 convert into MFMA-fragment-ordered layout ----------------
// For a [rows][Kd] row-major input, tile (256 rows x 64 k). Element (r,k):
//   bt=r>>8, rr=r&255, kt=k>>6, kr=k&63
//   frag = (rr>>4)*2 + (kr>>5)        // == (wr*8+mt)*2+kk == (wc*4+nt)*2+kk
//   lane = ((kr>>3)&3)*16 + (rr&15),  j = kr&7
//   flat = ((bt*(Kd/64)+kt)*32 + frag)*512 + lane*8 + j
// A wave's ds_read of one fragment is then base+lane*16B (conflict-free), and
// global_load_lds staging of a 32KB tile chunk is exactly linear.
__global__ __launch_bounds__(256) void cvt_frag_kernel(const float* __restrict__ in,
                                                       _Float16* __restrict__ out,
                                                       int n4, int Kd) {
  int i = blockIdx.x * 256 + threadIdx.x;
  if (i >= n4) return;
  int kq = Kd >> 2;
  int r = i / kq, k = (i - r * kq) * 4;
  float4 v = ((const float4*)in)[i];
  int bt = r >> 8, rr = r & 255;
  int kt = k >> 6, kr = k & 63;
  int frag = ((rr >> 4) << 1) + (kr >> 5);
  size_t flat = (((size_t)bt * (Kd >> 6) + kt) * 32 + frag) * 512
              + ((((kr >> 3) & 3) * 16 + (rr & 15)) << 3) + (kr & 7);
  half4v h;
  h[0] = (_Float16)v.x; h[1] = (_Float16)v.y; h[2] = (_Float16)v.z; h[3] = (_Float16)v.w;
  *(half4v*)(out + flat) = h;
}

// ---------------- 8-phase 256x256 GEMM (gemm1): C = A * B^T ----------------
// A2/B2 are fragment-ordered (cvt_frag layout). 512 threads = 8 waves (2Mx4N),
// per-wave output 128x64, BK=64, double-buffered 128KB dynamic LDS.
// Per K-tile: s_waitcnt vmcnt(0) (waits loads issued 2-3 phases earlier) ->
// s_barrier -> 4 phases {12 ds_read + (4 gload next tile at ph 0/1) -> barrier
// -> setprio(1) 16 MFMA setprio(0) -> barrier}. Raw barriers: no vmcnt drain.
__global__ __launch_bounds__(512, 2) void gemm8p(const _Float16* __restrict__ A2,
                                                 const _Float16* __restrict__ B2,
                                                 _Float16* __restrict__ Cc,
                                                 int M, int Nn, int K, int nbx) {
  extern __shared__ _Float16 lds[];   // A: [0,32768) f16 (2 bufs), B: [32768,65536)
  const int tid = threadIdx.x;
  const int lane = tid & 63, w = tid >> 6;
  const int l15 = lane & 15, l4 = lane >> 4;
  const int wr = w >> 2, wc = w & 3;           // 2 x 4 waves
  int nwg = gridDim.x, cpx = nwg >> 3;
  int wg = (blockIdx.x & 7) * cpx + (blockIdx.x >> 3);   // bijective XCD swizzle
  const int bm = wg % nbx, bn = wg / nbx;
  const int ktiles = K >> 6;
  const _Float16* Abase = A2 + (size_t)bm * ktiles * 16384 + tid * 8;
  const _Float16* Bbase = B2 + (size_t)bn * ktiles * 16384 + tid * 8;
  f32x4 acc[8][4] = {};
  auto stageA = [&](int kt, int buf) {
    const _Float16* s = Abase + (size_t)kt * 16384;
    _Float16* d = lds + buf * 16384 + tid * 8;
#pragma unroll
    for (int i = 0; i < 4; ++i) GLOAD_LDS16(s + i * 4096, d + i * 4096);
  };
  auto stageB = [&](int kt, int buf) {
    const _Float16* s = Bbase + (size_t)kt * 16384;
    _Float16* d = lds + 32768 + buf * 16384 + tid * 8;
#pragma unroll
    for (int i = 0; i < 4; ++i) GLOAD_LDS16(s + i * 4096, d + i * 4096);
  };
  stageA(0, 0);
  stageB(0, 0);
  for (int kt = 0; kt < ktiles; ++kt) {
    const int cur = kt & 1, nxt = cur ^ 1;
    const _Float16* Ac = lds + cur * 16384 + lane * 8;
    const _Float16* Bc = lds + 32768 + cur * 16384 + lane * 8;
    asm volatile("s_waitcnt vmcnt(0)" ::: "memory");   // my stage of tile kt done
    __builtin_amdgcn_sched_barrier(0);
    __builtin_amdgcn_s_barrier();                       // everyone's stage done;
    __builtin_amdgcn_sched_barrier(0);                  // prior buf reads done
#pragma unroll
    for (int ph = 0; ph < 4; ++ph) {
      const int mh = ph >> 1, nh = ph & 1;
      half8 af[4][2], bf[2][2];
#pragma unroll
      for (int mt = 0; mt < 4; ++mt)
#pragma unroll
        for (int kk = 0; kk < 2; ++kk)
          af[mt][kk] = *(half8*)(Ac + ((((wr * 8 + mh * 4 + mt) << 1) + kk) << 9));
#pragma unroll
      for (int nt = 0; nt < 2; ++nt)
#pragma unroll
        for (int kk = 0; kk < 2; ++kk)
          bf[nt][kk] = *(half8*)(Bc + ((((wc * 4 + nh * 2 + nt) << 1) + kk) << 9));
      if (ph == 0 && kt + 1 < ktiles) stageA(kt + 1, nxt);
      if (ph == 1 && kt + 1 < ktiles) stageB(kt + 1, nxt);
      __builtin_amdgcn_s_barrier();
      __builtin_amdgcn_s_setprio(1);
#pragma unroll
      for (int mt = 0; mt < 4; ++mt)
#pragma unroll
        for (int nt = 0; nt < 2; ++nt)
#pragma unroll
          for (int kk = 0; kk < 2; ++kk)
            acc[mh * 4 + mt][nh * 2 + nt] = __builtin_amdgcn_mfma_f32_16x16x32_f16(
                af[mt][kk], bf[nt][kk], acc[mh * 4 + mt][nh * 2 + nt], 0, 0, 0);
      __builtin_amdgcn_s_setprio(0);
      __builtin_amdgcn_s_barrier();
    }
  }
#pragma unroll
  for (int mt8 = 0; mt8 < 8; ++mt8)
#pragma unroll
    for (int nt4 = 0; nt4 < 4; ++nt4)
#pragma unroll
      for (int r = 0; r < 4; ++r) {
        int row = bm * 256 + wr * 128 + mt8 * 16 + l4 * 4 + r;
        int col = bn * 256 + wc * 64 + nt4 * 16 + l15;
        Cc[(size_t)row * Nn + col] = (_Float16)acc[mt8][nt4][r];
      }
}

// ---------------- GEMM (gemm2): C[M][Nn] = A[M][K] * Bt[Nn][K]^T ----------------
// 128x128 tile, BK=32, linear LDS, global_load_lds width-16, 2-phase dbuf,
// bijective XCD swizzle. Row-major A/Bt.
template <typename OutT>
__global__ __launch_bounds__(256) void gemm_bt(const _Float16* __restrict__ A,
                                               const _Float16* __restrict__ Bt,
                                               OutT* __restrict__ Cc,
                                               int M, int Nn, int K, int nbx) {
  __shared__ _Float16 As[2][128][32];
  __shared__ _Float16 Bs[2][128][32];
  const int tid = threadIdx.x;
  const int lane = tid & 63, w = tid >> 6;
  const int l15 = lane & 15, l4 = lane >> 4;
  int nwg = gridDim.x, cpx = nwg >> 3;
  int wg = (blockIdx.x & 7) * cpx + (blockIdx.x >> 3);
  const int m0 = (wg % nbx) * 128, n0 = (wg / nbx) * 128;
  const int wr = w >> 1, wc = w & 1;
  const int rb = w * 32;
  const int rl = lane >> 2;
  const int cb = (lane & 3) * 8;
  f32x4 acc[4][4] = {};
  auto stage = [&](int k0, int buf) {
    GLOAD_LDS16(A  + (size_t)(m0 + rb + rl) * K + k0 + cb,      &As[buf][rb][0]);
    GLOAD_LDS16(A  + (size_t)(m0 + rb + 16 + rl) * K + k0 + cb, &As[buf][rb + 16][0]);
    GLOAD_LDS16(Bt + (size_t)(n0 + rb + rl) * K + k0 + cb,      &Bs[buf][rb][0]);
    GLOAD_LDS16(Bt + (size_t)(n0 + rb + 16 + rl) * K + k0 + cb, &Bs[buf][rb + 16][0]);
  };
  auto compute = [&](int buf) {
    half8 af[4], bf[4];
#pragma unroll
    for (int mt = 0; mt < 4; ++mt) af[mt] = *(half8*)&As[buf][wr * 64 + mt * 16 + l15][l4 * 8];
#pragma unroll
    for (int nt = 0; nt < 4; ++nt) bf[nt] = *(half8*)&Bs[buf][wc * 64 + nt * 16 + l15][l4 * 8];
#pragma unroll
    for (int mt = 0; mt < 4; ++mt)
#pragma unroll
      for (int nt = 0; nt < 4; ++nt)
        acc[mt][nt] = __builtin_amdgcn_mfma_f32_16x16x32_f16(af[mt], bf[nt], acc[mt][nt], 0, 0, 0);
  };
  stage(0, 0);
  __syncthreads();
  for (int k0 = 0; k0 < K; k0 += 64) {
    stage(k0 + 32, 1);
    compute(0);
    __syncthreads();
    if (k0 + 64 < K) stage(k0 + 64, 0);
    compute(1);
    __syncthreads();
  }
#pragma unroll
  for (int mt = 0; mt < 4; ++mt)
#pragma unroll
    for (int nt = 0; nt < 4; ++nt)
#pragma unroll
      for (int r = 0; r < 4; ++r) {
        int row = m0 + wr * 64 + mt * 16 + l4 * 4 + r;
        int col = n0 + wc * 64 + nt * 16 + l15;
        Cc[(size_t)row * Nn + col] = (OutT)acc[mt][nt][r];
      }
}

// ---------------- fused RMSNorm + RoPE for Q,K ----------------
// one wave per (n, h); lane = d. Q row-major pre-scaled by 0.125*log2(e).
// K written into fragment-swizzled KF layout (see attn_kernel header).
__global__ __launch_bounds__(256) void rmsrope_kernel(const _Float16* __restrict__ qkv,
                                                      const int* __restrict__ coords,
                                                      const float* __restrict__ gq,
                                                      const float* __restrict__ gk,
                                                      _Float16* __restrict__ Qh,
                                                      _Float16* __restrict__ KF) {
  int gw = blockIdx.x * 4 + (threadIdx.x >> 6);
  int lane = threadIdx.x & 63;
  int n = gw >> 4, h = gw & 15;
  float q = (float)qkv[(size_t)n * C3 + h * HD + lane];
  float k = (float)qkv[(size_t)n * C3 + CH + h * HD + lane];
  float sq = q * q, sk = k * k;
#pragma unroll
  for (int m = 1; m < 64; m <<= 1) { sq += __shfl_xor(sq, m); sk += __shfl_xor(sk, m); }
  q *= 8.0f / fmaxf(sqrtf(sq), 1e-12f) * gq[h * HD + lane];
  k *= 8.0f / fmaxf(sqrtf(sk), 1e-12f) * gk[h * HD + lane];
  int j = lane >> 1, p = j >> 3, dr = j & 7;
  float ang = (float)coords[n * 5 + 1 + p] * __expf(-(float)dr * 0.14391157f);
  float cs = cosf(ang), sn = sinf(ang);
  float qp = __shfl_xor(q, 1), kp = __shfl_xor(k, 1);
  float qr, kr;
  if ((lane & 1) == 0) { qr = q * cs - qp * sn; kr = k * cs - kp * sn; }
  else                 { qr = qp * sn + q * cs; kr = kp * sn + k * cs; }
  Qh[((size_t)h * NT + n) * HD + lane] = (_Float16)(qr * 0.18033688f);  // 0.125*log2e
  // KF fragment-swizzle: key m=n&63 -> (t, i15); d=lane -> (kk, l4, j)
  int m64 = n & 63, kb = n >> 6;
  int t   = 2 * (m64 >> 5) + ((m64 >> 2) & 1);
  int i15 = 4 * ((m64 >> 3) & 3) + (m64 & 3);
  int kk = lane >> 5, ll4 = (lane >> 3) & 3, jj = lane & 7;
  KF[(size_t)h * NT * HD + (size_t)kb * 4096 +
     (size_t)(((t * 2 + kk) * 64 + ll4 * 16 + i15) * 8 + jj)] = (_Float16)kr;
}

// ---------------- V into fragment-swizzled VF layout ----------------
__global__ __launch_bounds__(256) void vtrans_kernel(const _Float16* __restrict__ qkv,
                                                     _Float16* __restrict__ VF) {
  __shared__ _Float16 L[64][72];
  int h = blockIdx.y, n0 = blockIdx.x * 64, kb = blockIdx.x, t0 = threadIdx.x;
#pragma unroll
  for (int i = 0; i < 2; ++i) {
    int cid = t0 + i * 256, r = cid >> 3, c = cid & 7;
    *(half8*)&L[r][c * 8] = *(const half8*)(qkv + (size_t)(n0 + r) * C3 + 2 * CH + h * HD + c * 8);
  }
  __syncthreads();
#pragma unroll
  for (int i = 0; i < 2; ++i) {
    int cid = t0 + i * 256, d = cid >> 3, c = cid & 7;
    half8 v;
#pragma unroll
    for (int jj = 0; jj < 8; ++jj) v[jj] = L[c * 8 + jj][d];
    size_t flat = (size_t)h * NT * HD + (size_t)kb * 4096 +
                  (size_t)((((d >> 4) * 2 + (c >> 2)) * 64 + (c & 3) * 16 + (d & 15)) * 8);
    *(half8*)(VF + flat) = v;
  }
}

// ---------------- flash attention: single-buffer gload_lds (r10, best measured) ----------------
__global__ __launch_bounds__(256, 2) void attn_kernel(const _Float16* __restrict__ Qh,
                                                      const _Float16* __restrict__ KF,
                                                      const _Float16* __restrict__ VF,
                                                      _Float16* __restrict__ Oh) {
  __shared__ _Float16 KB[4096];
  __shared__ _Float16 VB[4096];
  const int tid = threadIdx.x, lane = tid & 63, w = tid >> 6;
  const int l15 = lane & 15, l4 = lane >> 4;
  int bid = blockIdx.x;
  int s = bid >> 3;
  int h = (bid & 7) * 2 + (s >> 5);
  int n0 = (s & 31) * 128;
  half8 qf[2][2];
#pragma unroll
  for (int qb = 0; qb < 2; ++qb)
#pragma unroll
    for (int kk = 0; kk < 2; ++kk)
      qf[qb][kk] = *(const half8*)(Qh + ((size_t)h * NT + n0 + w * 32 + qb * 16 + l15) * HD + kk * 32 + l4 * 8);
  f32x4 acc[2][4] = {};
  f32x4 acc5[2] = {};
  half8 of1 = {};
  if (l15 == 0) {
#pragma unroll
    for (int jq = 0; jq < 8; ++jq) of1[jq] = (_Float16)1.0f;
  }
  const _Float16* KFh = KF + (size_t)h * NT * HD + w * 512 + lane * 8;
  const _Float16* VFh = VF + (size_t)h * NT * HD + w * 512 + lane * 8;
  union U { half8 v; half2 p[4]; };
  for (int kb = 0; kb < 64; ++kb) {
    __syncthreads();
    {
      size_t g0 = (size_t)kb * 4096;
      GLOAD_LDS16(KFh + g0,        &KB[w * 512]);
      GLOAD_LDS16(KFh + g0 + 2048, &KB[2048 + w * 512]);
      GLOAD_LDS16(VFh + g0,        &VB[w * 512]);
      GLOAD_LDS16(VFh + g0 + 2048, &VB[2048 + w * 512]);
    }
    __syncthreads();
    f32x4 sv[2][4] = {};
    __builtin_amdgcn_s_setprio(1);
#pragma unroll
    for (int t = 0; t < 4; ++t)
#pragma unroll
      for (int kk = 0; kk < 2; ++kk) {
        half8 kf = *(half8*)&KB[(t * 2 + kk) * 512 + lane * 8];
        sv[0][t] = __builtin_amdgcn_mfma_f32_16x16x32_f16(kf, qf[0][kk], sv[0][t], 0, 0, 0);
        sv[1][t] = __builtin_amdgcn_mfma_f32_16x16x32_f16(kf, qf[1][kk], sv[1][t], 0, 0, 0);
      }
    __builtin_amdgcn_s_setprio(0);
    U u[2][2];
#pragma unroll
    for (int qb = 0; qb < 2; ++qb) {
      float e[4][4];
#pragma unroll
      for (int t = 0; t < 4; ++t)
#pragma unroll
        for (int r = 0; r < 4; ++r) e[t][r] = EXP2(sv[qb][t][r]);
      u[qb][0].p[0] = pk_f16(e[0][0], e[0][1]); u[qb][0].p[1] = pk_f16(e[0][2], e[0][3]);
      u[qb][0].p[2] = pk_f16(e[1][0], e[1][1]); u[qb][0].p[3] = pk_f16(e[1][2], e[1][3]);
      u[qb][1].p[0] = pk_f16(e[2][0], e[2][1]); u[qb][1].p[1] = pk_f16(e[2][2], e[2][3]);
      u[qb][1].p[2] = pk_f16(e[3][0], e[3][1]); u[qb][1].p[3] = pk_f16(e[3][2], e[3][3]);
    }
    __builtin_amdgcn_s_setprio(1);
#pragma unroll
    for (int t = 0; t < 4; ++t)
#pragma unroll
      for (int kk = 0; kk < 2; ++kk) {
        half8 vf = *(half8*)&VB[(t * 2 + kk) * 512 + lane * 8];
        acc[0][t] = __builtin_amdgcn_mfma_f32_16x16x32_f16(u[0][kk].v, vf, acc[0][t], 0, 0, 0);
        acc[1][t] = __builtin_amdgcn_mfma_f32_16x16x32_f16(u[1][kk].v, vf, acc[1][t], 0, 0, 0);
      }
    acc5[0] = __builtin_amdgcn_mfma_f32_16x16x32_f16(u[0][0].v, of1, acc5[0], 0, 0, 0);
    acc5[0] = __builtin_amdgcn_mfma_f32_16x16x32_f16(u[0][1].v, of1, acc5[0], 0, 0, 0);
    acc5[1] = __builtin_amdgcn_mfma_f32_16x16x32_f16(u[1][0].v, of1, acc5[1], 0, 0, 0);
    acc5[1] = __builtin_amdgcn_mfma_f32_16x16x32_f16(u[1][1].v, of1, acc5[1], 0, 0, 0);
    __builtin_amdgcn_s_setprio(0);
  }
#pragma unroll
  for (int qb = 0; qb < 2; ++qb) {
    float linv[4];
#pragma unroll
    for (int r = 0; r < 4; ++r) linv[r] = 1.0f / __shfl(acc5[qb][r], lane & 48);
#pragma unroll
    for (int t = 0; t < 4; ++t)
#pragma unroll
      for (int r = 0; r < 4; ++r) {
        int row = n0 + w * 32 + qb * 16 + l4 * 4 + r;
        Oh[(size_t)row * CH + h * HD + t * 16 + l15] = (_Float16)(acc[qb][t][r] * linv[r]);
      }
  }
}

extern "C" void kernel_launch(void* const* d_in, const int* in_sizes, int n_in,
                              void* d_out, int out_size, void* d_ws, size_t ws_size,
                              hipStream_t stream) {
  const float* x      = (const float*)d_in[0];
  const int*   coords = (const int*)d_in[1];
  const float* w_qkv  = (const float*)d_in[2];
  const float* w_out  = (const float*)d_in[3];
  const float* gq     = (const float*)d_in[4];
  const float* gk     = (const float*)d_in[5];
  float* out = (float*)d_out;

  char* ws = (char*)d_ws;
  size_t off = 0;
  auto alloc = [&](size_t bytes) { char* p = ws + off; off += bytes; return p; };
  _Float16* xh   = (_Float16*)alloc((size_t)NT * CH * 2);  // x, frag-ordered
  _Float16* wqh  = (_Float16*)alloc((size_t)C3 * CH * 2);  // w_qkv, frag-ordered
  _Float16* woh  = (_Float16*)alloc((size_t)CH * CH * 2);  // w_out, row-major
  _Float16* qkvh = (_Float16*)alloc((size_t)NT * C3 * 2);  // qkv f16 row-major
  _Float16* Qh   = (_Float16*)alloc((size_t)NT * CH * 2);  // [H][N][64], pre-scaled
  _Float16* KFh  = (_Float16*)alloc((size_t)NT * CH * 2);  // frag-swizzled K
  _Float16* VFh  = (_Float16*)alloc((size_t)NT * CH * 2);  // frag-swizzled V
  _Float16* Oh   = (_Float16*)alloc((size_t)NT * CH * 2);  // attn out [N][C]
  if (off > ws_size) return;

  cvt_frag_kernel<<<NT * CH / 4 / 256, 256, 0, stream>>>(x, xh, NT * CH / 4, CH);
  cvt_frag_kernel<<<C3 * CH / 4 / 256, 256, 0, stream>>>(w_qkv, wqh, C3 * CH / 4, CH);
  cvt_kernel<<<CH * CH / 4 / 256, 256, 0, stream>>>(w_out, woh, CH * CH / 4);
  gemm8p<<<(NT / 256) * (C3 / 256), 512, 131072, stream>>>(xh, wqh, qkvh, NT, C3, CH, NT / 256);
  rmsrope_kernel<<<NT * NH / 4, 256, 0, stream>>>(qkvh, coords, gq, gk, Qh, KFh);
  vtrans_kernel<<<dim3(NT / 64, NH), 256, 0, stream>>>(qkvh, VFh);
  attn_kernel<<<NH * (NT / 128), 256, 0, stream>>>(Qh, KFh, VFh, Oh);
  gemm_bt<float><<<(NT / 128) * (CH / 128), 256, 0, stream>>>(Oh, woh, out, NT, CH, CH, NT / 128);
}

// Round 16
// 163.861 us; speedup vs baseline: 1.2010x; 1.1160x over previous
//
#include <hip/hip_runtime.h>
#include <hip/hip_bf16.h>

typedef _Float16 half8 __attribute__((ext_vector_type(8)));
typedef _Float16 half4v __attribute__((ext_vector_type(4)));
typedef _Float16 half2 __attribute__((ext_vector_type(2)));
typedef float f32x4 __attribute__((ext_vector_type(4)));

constexpr int NT = 4096;   // tokens
constexpr int CH = 1024;   // channels
constexpr int NH = 16;     // heads
constexpr int HD = 64;     // head dim
constexpr int C3 = 3072;   // 3*CH

#if __has_builtin(__builtin_amdgcn_exp2f)
#define EXP2(x) __builtin_amdgcn_exp2f(x)
#else
#define EXP2(x) exp2f(x)
#endif

#define GLOAD_LDS16(gp, lp) __builtin_amdgcn_global_load_lds( \
    (const __attribute__((address_space(1))) void*)(gp),      \
    (__attribute__((address_space(3))) void*)(lp), 16, 0, 0)

static __device__ inline half2 pk_f16(float a, float b) {
  auto r = __builtin_amdgcn_cvt_pkrtz(a, b);   // v_cvt_pkrtz_f16_f32
  return *(half2*)&r;
}

// ---------------- fused f32 -> f16 convert (x, w_qkv, w_out in one launch) ----------------
__global__ __launch_bounds__(256) void cvt3_kernel(const float* __restrict__ a, int na4,
                                                   const float* __restrict__ b, int nb4,
                                                   const float* __restrict__ c, int nc4,
                                                   _Float16* __restrict__ oa,
                                                   _Float16* __restrict__ ob,
                                                   _Float16* __restrict__ oc) {
  int i = blockIdx.x * 256 + threadIdx.x;
  const float* src; _Float16* dst; int j = i;
  if (i < na4) { src = a; dst = oa; }
  else if (i < na4 + nb4) { src = b; dst = ob; j = i - na4; }
  else if (i < na4 + nb4 + nc4) { src = c; dst = oc; j = i - na4 - nb4; }
  else return;
  float4 v = ((const float4*)src)[j];
  half4v h;
  h[0] = (_Float16)v.x; h[1] = (_Float16)v.y; h[2] = (_Float16)v.z; h[3] = (_Float16)v.w;
  ((half4v*)dst)[j] = h;
}

// ---------------- RoPE cos/sin table: csn[n*32 + j] = {cos, sin}(ang(n,j)) ----------------
// j = (d>>1) in [0,32): p = j>>3 selects coords col 1+p, dr = j&7 the freq.
__global__ __launch_bounds__(256) void rope_tab_kernel(const int* __restrict__ coords,
                                                       float2* __restrict__ csn) {
  int idx = blockIdx.x * 256 + threadIdx.x;   // NT*32 exact
  int n = idx >> 5, j = idx & 31;
  float ang = (float)coords[n * 5 + 1 + (j >> 3)] * __expf(-(float)(j & 7) * 0.14391157f);
  csn[idx] = make_float2(cosf(ang), sinf(ang));
}

// ---------------- fused QKV GEMM + RMSNorm + RoPE + K/V fragment-swizzle ----------------
// C = x @ w_qkv^T (4096 x 3072), 128x128 tiles, 2-phase gload_lds staging,
// bijective XCD swizzle. Each wave's 64-col sub-tile is exactly ONE head of
// ONE section (sec = col>>10: 0=q,1=k,2=v; uniform per block). Epilogue:
//   q/k: row 64-d norm (4 partials + 4x shfl_xor over l15 group), *gamma*8/nrm,
//        RoPE via csn table (pair partner = shfl_xor(val,1));
//        q additionally scaled 0.125*log2e.
//   all: route tile through per-wave LDS [64][72] -> emit Qh row-major f16,
//        KF/VF in the fragment-swizzled layouts attn consumes (same formulas
//        as the verified rmsrope/vtrans kernels).
__global__ __launch_bounds__(256) void gemm_qkv(const _Float16* __restrict__ A,
                                                const _Float16* __restrict__ Bt,
                                                const float2* __restrict__ csn,
                                                const float* __restrict__ gq,
                                                const float* __restrict__ gk,
                                                _Float16* __restrict__ Qh,
                                                _Float16* __restrict__ KF,
                                                _Float16* __restrict__ VF) {
  __shared__ __align__(16) char smem[36864];
  auto As = (_Float16(*)[128][32])smem;               // [2][128][32] = 16KB
  auto Bs = (_Float16(*)[128][32])(smem + 16384);     // [2][128][32] = 16KB
  const int K = CH, Nn = C3, nbx = NT / 128;
  const int tid = threadIdx.x;
  const int lane = tid & 63, w = tid >> 6;
  const int l15 = lane & 15, l4 = lane >> 4;
  int nwg = gridDim.x, cpx = nwg >> 3;
  int wg = (blockIdx.x & 7) * cpx + (blockIdx.x >> 3);
  const int m0 = (wg % nbx) * 128, n0 = (wg / nbx) * 128;
  const int wr = w >> 1, wc = w & 1;
  const int rb = w * 32;
  const int rl = lane >> 2;
  const int cb = (lane & 3) * 8;
  f32x4 acc[4][4] = {};
  auto stage = [&](int k0, int buf) {
    GLOAD_LDS16(A  + (size_t)(m0 + rb + rl) * K + k0 + cb,      &As[buf][rb][0]);
    GLOAD_LDS16(A  + (size_t)(m0 + rb + 16 + rl) * K + k0 + cb, &As[buf][rb + 16][0]);
    GLOAD_LDS16(Bt + (size_t)(n0 + rb + rl) * K + k0 + cb,      &Bs[buf][rb][0]);
    GLOAD_LDS16(Bt + (size_t)(n0 + rb + 16 + rl) * K + k0 + cb, &Bs[buf][rb + 16][0]);
  };
  auto compute = [&](int buf) {
    half8 af[4], bf[4];
#pragma unroll
    for (int mt = 0; mt < 4; ++mt) af[mt] = *(half8*)&As[buf][wr * 64 + mt * 16 + l15][l4 * 8];
#pragma unroll
    for (int nt = 0; nt < 4; ++nt) bf[nt] = *(half8*)&Bs[buf][wc * 64 + nt * 16 + l15][l4 * 8];
#pragma unroll
    for (int mt = 0; mt < 4; ++mt)
#pragma unroll
      for (int nt = 0; nt < 4; ++nt)
        acc[mt][nt] = __builtin_amdgcn_mfma_f32_16x16x32_f16(af[mt], bf[nt], acc[mt][nt], 0, 0, 0);
  };
  stage(0, 0);
  __syncthreads();
  for (int k0 = 0; k0 < K; k0 += 64) {
    stage(k0 + 32, 1);
    compute(0);
    __syncthreads();
    if (k0 + 64 < K) stage(k0 + 64, 0);
    compute(1);
    __syncthreads();
  }
  // ---- fused epilogue (per-wave private LDS region; no cross-wave sharing) ----
  const int gc0 = n0 + wc * 64;
  const int sec = gc0 >> 10;                 // 0=q, 1=k, 2=v
  const int h   = (gc0 & 1023) >> 6;
  const int K0  = m0 + wr * 64;              // token base of this wave's rows
  _Float16* Lw = (_Float16*)(smem + w * 9216);   // [64][72] f16
  if (sec < 2) {                             // ---- Q/K: RMSNorm + RoPE ----
    const float* gm = (sec == 0) ? gq : gk;
    float gmm[4];
#pragma unroll
    for (int nt = 0; nt < 4; ++nt) gmm[nt] = gm[h * 64 + nt * 16 + l15];
    const float qsc = (sec == 0) ? 0.18033688f : 1.0f;   // 0.125*log2(e) for Q
#pragma unroll
    for (int mt = 0; mt < 4; ++mt)
#pragma unroll
      for (int r = 0; r < 4; ++r) {
        float ss = 0.f;
#pragma unroll
        for (int nt = 0; nt < 4; ++nt) ss += acc[mt][nt][r] * acc[mt][nt][r];
        ss += __shfl_xor(ss, 1); ss += __shfl_xor(ss, 2);
        ss += __shfl_xor(ss, 4); ss += __shfl_xor(ss, 8);
        float sc = 8.0f / fmaxf(sqrtf(ss), 1e-12f);
        int row = mt * 16 + l4 * 4 + r;      // local token row
        int n = K0 + row;
#pragma unroll
        for (int nt = 0; nt < 4; ++nt) {
          float v = acc[mt][nt][r] * sc * gmm[nt];
          float2 cz = csn[n * 32 + nt * 8 + (l15 >> 1)];
          float p = __shfl_xor(v, 1);
          float o = ((l15 & 1) == 0) ? (v * cz.x - p * cz.y) : (p * cz.y + v * cz.x);
          Lw[row * 72 + nt * 16 + l15] = (_Float16)(o * qsc);
        }
      }
  } else {                                   // ---- V: passthrough ----
#pragma unroll
    for (int mt = 0; mt < 4; ++mt)
#pragma unroll
      for (int r = 0; r < 4; ++r) {
        int row = mt * 16 + l4 * 4 + r;
#pragma unroll
        for (int nt = 0; nt < 4; ++nt)
          Lw[row * 72 + nt * 16 + l15] = (_Float16)acc[mt][nt][r];
      }
  }
  // within-wave LDS write->read: lockstep program order, no barrier needed
  const int kb = K0 >> 6;
  if (sec == 0) {                            // Q row-major: [h][NT][64]
#pragma unroll
    for (int i = 0; i < 8; ++i) {
      int row = i * 8 + (lane >> 3), col = (lane & 7) * 8;
      half8 vv = *(half8*)&Lw[row * 72 + col];
      *(half8*)(Qh + ((size_t)h * NT + K0 + row) * 64 + col) = vv;
    }
  } else if (sec == 1) {                     // K fragment-swizzled
    _Float16* base = KF + (size_t)h * NT * HD + (size_t)kb * 4096;
#pragma unroll
    for (int i = 0; i < 8; ++i) {
      int t = i >> 1, kk = i & 1;
      int i15 = lane & 15, ll4 = lane >> 4;
      // invert: t=2*(m>>5)+((m>>2)&1); i15=4*((m>>3)&3)+(m&3)
      int m = ((t >> 1) << 5) | ((i15 >> 2) << 3) | ((t & 1) << 2) | (i15 & 3);
      half8 vv = *(half8*)&Lw[m * 72 + kk * 32 + ll4 * 8];
      *(half8*)(base + (size_t)(((t * 2 + kk) * 64 + ll4 * 16 + i15) * 8)) = vv;
    }
  } else {                                   // V fragment-swizzled
    _Float16* base = VF + (size_t)h * NT * HD + (size_t)kb * 4096;
#pragma unroll
    for (int i = 0; i < 8; ++i) {
      int t = i >> 1, kk = i & 1;
      int l15v = lane & 15, l4v = lane >> 4;
      half8 vv;
#pragma unroll
      for (int jj = 0; jj < 8; ++jj)
        vv[jj] = Lw[(kk * 32 + l4v * 8 + jj) * 72 + t * 16 + l15v];
      *(half8*)(base + (size_t)(((t * 2 + kk) * 64 + l4v * 16 + l15v) * 8)) = vv;
    }
  }
}

// ---------------- GEMM (gemm2): C[M][Nn] = A[M][K] * Bt[Nn][K]^T ----------------
// 128x128 tile, BK=32, linear LDS, global_load_lds width-16, 2-phase dbuf,
// bijective XCD swizzle (nwg % 8 == 0). K % 64 == 0.
template <typename OutT>
__global__ __launch_bounds__(256) void gemm_bt(const _Float16* __restrict__ A,
                                               const _Float16* __restrict__ Bt,
                                               OutT* __restrict__ Cc,
                                               int M, int Nn, int K, int nbx) {
  __shared__ _Float16 As[2][128][32];
  __shared__ _Float16 Bs[2][128][32];
  const int tid = threadIdx.x;
  const int lane = tid & 63, w = tid >> 6;
  const int l15 = lane & 15, l4 = lane >> 4;
  int nwg = gridDim.x, cpx = nwg >> 3;
  int wg = (blockIdx.x & 7) * cpx + (blockIdx.x >> 3);
  const int m0 = (wg % nbx) * 128, n0 = (wg / nbx) * 128;
  const int wr = w >> 1, wc = w & 1;
  const int rb = w * 32;
  const int rl = lane >> 2;
  const int cb = (lane & 3) * 8;
  f32x4 acc[4][4] = {};
  auto stage = [&](int k0, int buf) {
    GLOAD_LDS16(A  + (size_t)(m0 + rb + rl) * K + k0 + cb,      &As[buf][rb][0]);
    GLOAD_LDS16(A  + (size_t)(m0 + rb + 16 + rl) * K + k0 + cb, &As[buf][rb + 16][0]);
    GLOAD_LDS16(Bt + (size_t)(n0 + rb + rl) * K + k0 + cb,      &Bs[buf][rb][0]);
    GLOAD_LDS16(Bt + (size_t)(n0 + rb + 16 + rl) * K + k0 + cb, &Bs[buf][rb + 16][0]);
  };
  auto compute = [&](int buf) {
    half8 af[4], bf[4];
#pragma unroll
    for (int mt = 0; mt < 4; ++mt) af[mt] = *(half8*)&As[buf][wr * 64 + mt * 16 + l15][l4 * 8];
#pragma unroll
    for (int nt = 0; nt < 4; ++nt) bf[nt] = *(half8*)&Bs[buf][wc * 64 + nt * 16 + l15][l4 * 8];
#pragma unroll
    for (int mt = 0; mt < 4; ++mt)
#pragma unroll
      for (int nt = 0; nt < 4; ++nt)
        acc[mt][nt] = __builtin_amdgcn_mfma_f32_16x16x32_f16(af[mt], bf[nt], acc[mt][nt], 0, 0, 0);
  };
  stage(0, 0);
  __syncthreads();
  for (int k0 = 0; k0 < K; k0 += 64) {
    stage(k0 + 32, 1);
    compute(0);
    __syncthreads();
    if (k0 + 64 < K) stage(k0 + 64, 0);
    compute(1);
    __syncthreads();
  }
#pragma unroll
  for (int mt = 0; mt < 4; ++mt)
#pragma unroll
    for (int nt = 0; nt < 4; ++nt)
#pragma unroll
      for (int r = 0; r < 4; ++r) {
        int row = m0 + wr * 64 + mt * 16 + l4 * 4 + r;
        int col = n0 + wc * 64 + nt * 16 + l15;
        Cc[(size_t)row * Nn + col] = (OutT)acc[mt][nt][r];
      }
}

// ---------------- flash attention: single-buffer gload_lds (r13-exact, 81.7us) ----------------
__global__ __launch_bounds__(256, 2) void attn_kernel(const _Float16* __restrict__ Qh,
                                                      const _Float16* __restrict__ KF,
                                                      const _Float16* __restrict__ VF,
                                                      _Float16* __restrict__ Oh) {
  __shared__ _Float16 KB[4096];
  __shared__ _Float16 VB[4096];
  const int tid = threadIdx.x, lane = tid & 63, w = tid >> 6;
  const int l15 = lane & 15, l4 = lane >> 4;
  int bid = blockIdx.x;
  int s = bid >> 3;
  int h = (bid & 7) * 2 + (s >> 5);
  int n0 = (s & 31) * 128;
  half8 qf[2][2];
#pragma unroll
  for (int qb = 0; qb < 2; ++qb)
#pragma unroll
    for (int kk = 0; kk < 2; ++kk)
      qf[qb][kk] = *(const half8*)(Qh + ((size_t)h * NT + n0 + w * 32 + qb * 16 + l15) * HD + kk * 32 + l4 * 8);
  f32x4 acc[2][4] = {};
  f32x4 acc5[2] = {};
  half8 of1 = {};
  if (l15 == 0) {
#pragma unroll
    for (int jq = 0; jq < 8; ++jq) of1[jq] = (_Float16)1.0f;
  }
  const _Float16* KFh = KF + (size_t)h * NT * HD + w * 512 + lane * 8;
  const _Float16* VFh = VF + (size_t)h * NT * HD + w * 512 + lane * 8;
  union U { half8 v; half2 p[4]; };
  for (int kb = 0; kb < 64; ++kb) {
    __syncthreads();
    {
      size_t g0 = (size_t)kb * 4096;
      GLOAD_LDS16(KFh + g0,        &KB[w * 512]);
      GLOAD_LDS16(KFh + g0 + 2048, &KB[2048 + w * 512]);
      GLOAD_LDS16(VFh + g0,        &VB[w * 512]);
      GLOAD_LDS16(VFh + g0 + 2048, &VB[2048 + w * 512]);
    }
    __syncthreads();
    f32x4 sv[2][4] = {};
    __builtin_amdgcn_s_setprio(1);
#pragma unroll
    for (int t = 0; t < 4; ++t)
#pragma unroll
      for (int kk = 0; kk < 2; ++kk) {
        half8 kf = *(half8*)&KB[(t * 2 + kk) * 512 + lane * 8];
        sv[0][t] = __builtin_amdgcn_mfma_f32_16x16x32_f16(kf, qf[0][kk], sv[0][t], 0, 0, 0);
        sv[1][t] = __builtin_amdgcn_mfma_f32_16x16x32_f16(kf, qf[1][kk], sv[1][t], 0, 0, 0);
      }
    __builtin_amdgcn_s_setprio(0);
    U u[2][2];
#pragma unroll
    for (int qb = 0; qb < 2; ++qb) {
      float e[4][4];
#pragma unroll
      for (int t = 0; t < 4; ++t)
#pragma unroll
        for (int r = 0; r < 4; ++r) e[t][r] = EXP2(sv[qb][t][r]);
      u[qb][0].p[0] = pk_f16(e[0][0], e[0][1]); u[qb][0].p[1] = pk_f16(e[0][2], e[0][3]);
      u[qb][0].p[2] = pk_f16(e[1][0], e[1][1]); u[qb][0].p[3] = pk_f16(e[1][2], e[1][3]);
      u[qb][1].p[0] = pk_f16(e[2][0], e[2][1]); u[qb][1].p[1] = pk_f16(e[2][2], e[2][3]);
      u[qb][1].p[2] = pk_f16(e[3][0], e[3][1]); u[qb][1].p[3] = pk_f16(e[3][2], e[3][3]);
    }
    __builtin_amdgcn_s_setprio(1);
#pragma unroll
    for (int t = 0; t < 4; ++t)
#pragma unroll
      for (int kk = 0; kk < 2; ++kk) {
        half8 vf = *(half8*)&VB[(t * 2 + kk) * 512 + lane * 8];
        acc[0][t] = __builtin_amdgcn_mfma_f32_16x16x32_f16(u[0][kk].v, vf, acc[0][t], 0, 0, 0);
        acc[1][t] = __builtin_amdgcn_mfma_f32_16x16x32_f16(u[1][kk].v, vf, acc[1][t], 0, 0, 0);
      }
    acc5[0] = __builtin_amdgcn_mfma_f32_16x16x32_f16(u[0][0].v, of1, acc5[0], 0, 0, 0);
    acc5[0] = __builtin_amdgcn_mfma_f32_16x16x32_f16(u[0][1].v, of1, acc5[0], 0, 0, 0);
    acc5[1] = __builtin_amdgcn_mfma_f32_16x16x32_f16(u[1][0].v, of1, acc5[1], 0, 0, 0);
    acc5[1] = __builtin_amdgcn_mfma_f32_16x16x32_f16(u[1][1].v, of1, acc5[1], 0, 0, 0);
    __builtin_amdgcn_s_setprio(0);
  }
#pragma unroll
  for (int qb = 0; qb < 2; ++qb) {
    float linv[4];
#pragma unroll
    for (int r = 0; r < 4; ++r) linv[r] = 1.0f / __shfl(acc5[qb][r], lane & 48);
#pragma unroll
    for (int t = 0; t < 4; ++t)
#pragma unroll
      for (int r = 0; r < 4; ++r) {
        int row = n0 + w * 32 + qb * 16 + l4 * 4 + r;
        Oh[(size_t)row * CH + h * HD + t * 16 + l15] = (_Float16)(acc[qb][t][r] * linv[r]);
      }
  }
}

extern "C" void kernel_launch(void* const* d_in, const int* in_sizes, int n_in,
                              void* d_out, int out_size, void* d_ws, size_t ws_size,
                              hipStream_t stream) {
  const float* x      = (const float*)d_in[0];
  const int*   coords = (const int*)d_in[1];
  const float* w_qkv  = (const float*)d_in[2];
  const float* w_out  = (const float*)d_in[3];
  const float* gq     = (const float*)d_in[4];
  const float* gk     = (const float*)d_in[5];
  float* out = (float*)d_out;

  char* ws = (char*)d_ws;
  size_t off = 0;
  auto alloc = [&](size_t bytes) { char* p = ws + off; off += bytes; return p; };
  _Float16* xh   = (_Float16*)alloc((size_t)NT * CH * 2);  // x f16
  _Float16* wqh  = (_Float16*)alloc((size_t)C3 * CH * 2);  // w_qkv f16
  _Float16* woh  = (_Float16*)alloc((size_t)CH * CH * 2);  // w_out f16
  float2*   csn  = (float2*)alloc((size_t)NT * 32 * 8);    // rope cos/sin table
  _Float16* Qh   = (_Float16*)alloc((size_t)NT * CH * 2);  // [H][N][64], pre-scaled
  _Float16* KFh  = (_Float16*)alloc((size_t)NT * CH * 2);  // frag-swizzled K
  _Float16* VFh  = (_Float16*)alloc((size_t)NT * CH * 2);  // frag-swizzled V
  _Float16* Oh   = (_Float16*)alloc((size_t)NT * CH * 2);  // attn out [N][C]
  if (off > ws_size) return;  // workspace too small: fail cleanly

  int na4 = NT * CH / 4, nb4 = C3 * CH / 4, nc4 = CH * CH / 4;
  cvt3_kernel<<<(na4 + nb4 + nc4) / 256, 256, 0, stream>>>(x, na4, w_qkv, nb4, w_out, nc4,
                                                           xh, wqh, woh);
  rope_tab_kernel<<<NT * 32 / 256, 256, 0, stream>>>(coords, csn);
  gemm_qkv<<<(NT / 128) * (C3 / 128), 256, 0, stream>>>(xh, wqh, csn, gq, gk, Qh, KFh, VFh);
  attn_kernel<<<NH * (NT / 128), 256, 0, stream>>>(Qh, KFh, VFh, Oh);
  gemm_bt<float><<<(NT / 128) * (CH / 128), 256, 0, stream>>>(Oh, woh, out, NT, CH, CH, NT / 128);
}

// Round 17
// 154.113 us; speedup vs baseline: 1.2770x; 1.0633x over previous
//
#include <hip/hip_runtime.h>
#include <hip/hip_bf16.h>

typedef _Float16 half8 __attribute__((ext_vector_type(8)));
typedef _Float16 half4v __attribute__((ext_vector_type(4)));
typedef _Float16 half2 __attribute__((ext_vector_type(2)));
typedef float f32x4 __attribute__((ext_vector_type(4)));

constexpr int NT = 4096;   // tokens
constexpr int CH = 1024;   // channels
constexpr int NH = 16;     // heads
constexpr int HD = 64;     // head dim
constexpr int C3 = 3072;   // 3*CH

#if __has_builtin(__builtin_amdgcn_exp2f)
#define EXP2(x) __builtin_amdgcn_exp2f(x)
#else
#define EXP2(x) exp2f(x)
#endif

#define GLOAD_LDS16(gp, lp) __builtin_amdgcn_global_load_lds( \
    (const __attribute__((address_space(1))) void*)(gp),      \
    (__attribute__((address_space(3))) void*)(lp), 16, 0, 0)

static __device__ inline half2 pk_f16(float a, float b) {
  auto r = __builtin_amdgcn_cvt_pkrtz(a, b);   // v_cvt_pkrtz_f16_f32
  return *(half2*)&r;
}

// ---------------- fused f32 -> f16 convert (x, w_qkv, w_out in one launch) ----------------
__global__ __launch_bounds__(256) void cvt3_kernel(const float* __restrict__ a, int na4,
                                                   const float* __restrict__ b, int nb4,
                                                   const float* __restrict__ c, int nc4,
                                                   _Float16* __restrict__ oa,
                                                   _Float16* __restrict__ ob,
                                                   _Float16* __restrict__ oc) {
  int i = blockIdx.x * 256 + threadIdx.x;
  const float* src; _Float16* dst; int j = i;
  if (i < na4) { src = a; dst = oa; }
  else if (i < na4 + nb4) { src = b; dst = ob; j = i - na4; }
  else if (i < na4 + nb4 + nc4) { src = c; dst = oc; j = i - na4 - nb4; }
  else return;
  float4 v = ((const float4*)src)[j];
  half4v h;
  h[0] = (_Float16)v.x; h[1] = (_Float16)v.y; h[2] = (_Float16)v.z; h[3] = (_Float16)v.w;
  ((half4v*)dst)[j] = h;
}

// ---------------- RoPE cos/sin table: csn[n*32 + j] = {cos, sin}(ang(n,j)) ----------------
__global__ __launch_bounds__(256) void rope_tab_kernel(const int* __restrict__ coords,
                                                       float2* __restrict__ csn) {
  int idx = blockIdx.x * 256 + threadIdx.x;   // NT*32 exact
  int n = idx >> 5, j = idx & 31;
  float ang = (float)coords[n * 5 + 1 + (j >> 3)] * __expf(-(float)(j & 7) * 0.14391157f);
  csn[idx] = make_float2(cosf(ang), sinf(ang));
}

// ---------------- fused QKV GEMM (256x256) + RMSNorm + RoPE + K/V frag-swizzle ----------------
// C = x @ w_qkv^T (4096 x 3072), 256x256 tiles, 8 waves (2M x 4N), each wave a
// 128x64 output (acc[8][4]): 32 MFMA per 12 ds_read_b128 (2.67:1 density) and
// half the A/B cache re-read traffic vs 128^2. Schedule: proven 2-phase
// double-buffer gload_lds (BK=32). Grid 192 (%8==0), bijective XCD swizzle,
// 1 block/CU (2 waves/SIMD).
// Epilogue: wave's 64-col span = ONE head of ONE section (sec = gc0>>10);
// processes its 128 rows as two 64-row halves through a private LDS region:
//   q/k: row-norm (4 partials + 4x shfl_xor over l15), *gamma*8/nrm, RoPE via
//        csn table (pair partner = shfl_xor(v,1)); q scaled 0.125*log2e.
//   emits Qh row-major / KF / VF in the exact layouts attn consumes
//   (formulas identical to the r16-verified versions).
__global__ __launch_bounds__(512, 2) void gemm_qkv(const _Float16* __restrict__ A,
                                                   const _Float16* __restrict__ Bt,
                                                   const float2* __restrict__ csn,
                                                   const float* __restrict__ gq,
                                                   const float* __restrict__ gk,
                                                   _Float16* __restrict__ Qh,
                                                   _Float16* __restrict__ KF,
                                                   _Float16* __restrict__ VF) {
  __shared__ __align__(16) char smem[73728];          // GEMM: 64KB; epilogue: 8x9216
  auto As = (_Float16(*)[256][32])smem;               // [2][256][32] = 32KB
  auto Bs = (_Float16(*)[256][32])(smem + 32768);     // [2][256][32] = 32KB
  const int K = CH;
  const int tid = threadIdx.x;
  const int lane = tid & 63, w = tid >> 6;
  const int l15 = lane & 15, l4 = lane >> 4;
  int nwg = gridDim.x, cpx = nwg >> 3;
  int wg = (blockIdx.x & 7) * cpx + (blockIdx.x >> 3);
  const int nbx = NT / 256;                           // 16
  const int bm = wg % nbx, bn = wg / nbx;
  const int m0 = bm * 256, n0 = bn * 256;
  const int wr = w >> 2, wc = w & 3;                  // 2 x 4 waves
  const int rb = w * 32;           // wave's 32-row staging band (8 waves x 32 = 256)
  const int rl = lane >> 2;        // row within 16-row chunk (4 lanes/row)
  const int cb = (lane & 3) * 8;   // f16 col of this lane's 16B
  f32x4 acc[8][4] = {};
  auto stage = [&](int k0, int buf) {
    GLOAD_LDS16(A  + (size_t)(m0 + rb + rl) * K + k0 + cb,      &As[buf][rb][0]);
    GLOAD_LDS16(A  + (size_t)(m0 + rb + 16 + rl) * K + k0 + cb, &As[buf][rb + 16][0]);
    GLOAD_LDS16(Bt + (size_t)(n0 + rb + rl) * K + k0 + cb,      &Bs[buf][rb][0]);
    GLOAD_LDS16(Bt + (size_t)(n0 + rb + 16 + rl) * K + k0 + cb, &Bs[buf][rb + 16][0]);
  };
  auto compute = [&](int buf) {
    half8 af[8], bf[4];
#pragma unroll
    for (int mt = 0; mt < 8; ++mt) af[mt] = *(half8*)&As[buf][wr * 128 + mt * 16 + l15][l4 * 8];
#pragma unroll
    for (int nt = 0; nt < 4; ++nt) bf[nt] = *(half8*)&Bs[buf][wc * 64 + nt * 16 + l15][l4 * 8];
#pragma unroll
    for (int mt = 0; mt < 8; ++mt)
#pragma unroll
      for (int nt = 0; nt < 4; ++nt)
        acc[mt][nt] = __builtin_amdgcn_mfma_f32_16x16x32_f16(af[mt], bf[nt], acc[mt][nt], 0, 0, 0);
  };
  stage(0, 0);
  __syncthreads();
  for (int k0 = 0; k0 < K; k0 += 64) {
    stage(k0 + 32, 1);
    compute(0);
    __syncthreads();
    if (k0 + 64 < K) stage(k0 + 64, 0);
    compute(1);
    __syncthreads();
  }
  // ---- fused epilogue (per-wave private LDS region; all staging reads sealed
  //      by the final loop barrier) ----
  const int gc0 = n0 + wc * 64;
  const int sec = gc0 >> 10;                 // 0=q, 1=k, 2=v
  const int h   = (gc0 & 1023) >> 6;
  _Float16* Lw = (_Float16*)(smem + w * 9216);   // [64][72] f16
  float gmm[4];
  if (sec < 2) {
    const float* gm = (sec == 0) ? gq : gk;
#pragma unroll
    for (int nt = 0; nt < 4; ++nt) gmm[nt] = gm[h * 64 + nt * 16 + l15];
  }
  const float qsc = (sec == 0) ? 0.18033688f : 1.0f;   // 0.125*log2(e) for Q
#pragma unroll
  for (int half = 0; half < 2; ++half) {
    const int K0 = m0 + wr * 128 + half * 64;  // token base of this 64-row half
    if (sec < 2) {                             // ---- Q/K: RMSNorm + RoPE ----
#pragma unroll
      for (int mt = 0; mt < 4; ++mt)
#pragma unroll
        for (int r = 0; r < 4; ++r) {
          float ss = 0.f;
#pragma unroll
          for (int nt = 0; nt < 4; ++nt)
            ss += acc[half * 4 + mt][nt][r] * acc[half * 4 + mt][nt][r];
          ss += __shfl_xor(ss, 1); ss += __shfl_xor(ss, 2);
          ss += __shfl_xor(ss, 4); ss += __shfl_xor(ss, 8);
          float sc = 8.0f / fmaxf(sqrtf(ss), 1e-12f);
          int row = mt * 16 + l4 * 4 + r;      // local row in this half
          int n = K0 + row;
#pragma unroll
          for (int nt = 0; nt < 4; ++nt) {
            float v = acc[half * 4 + mt][nt][r] * sc * gmm[nt];
            float2 cz = csn[n * 32 + nt * 8 + (l15 >> 1)];
            float p = __shfl_xor(v, 1);
            float o = ((l15 & 1) == 0) ? (v * cz.x - p * cz.y) : (p * cz.y + v * cz.x);
            Lw[row * 72 + nt * 16 + l15] = (_Float16)(o * qsc);
          }
        }
    } else {                                   // ---- V: passthrough ----
#pragma unroll
      for (int mt = 0; mt < 4; ++mt)
#pragma unroll
        for (int r = 0; r < 4; ++r) {
          int row = mt * 16 + l4 * 4 + r;
#pragma unroll
          for (int nt = 0; nt < 4; ++nt)
            Lw[row * 72 + nt * 16 + l15] = (_Float16)acc[half * 4 + mt][nt][r];
        }
    }
    // within-wave LDS write->read: lockstep program order, no barrier needed
    const int kb = K0 >> 6;
    if (sec == 0) {                            // Q row-major: [h][NT][64]
#pragma unroll
      for (int i = 0; i < 8; ++i) {
        int row = i * 8 + (lane >> 3), col = (lane & 7) * 8;
        half8 vv = *(half8*)&Lw[row * 72 + col];
        *(half8*)(Qh + ((size_t)h * NT + K0 + row) * 64 + col) = vv;
      }
    } else if (sec == 1) {                     // K fragment-swizzled
      _Float16* base = KF + (size_t)h * NT * HD + (size_t)kb * 4096;
#pragma unroll
      for (int i = 0; i < 8; ++i) {
        int t = i >> 1, kk = i & 1;
        int i15 = lane & 15, ll4 = lane >> 4;
        // invert: t=2*(m>>5)+((m>>2)&1); i15=4*((m>>3)&3)+(m&3)
        int m = ((t >> 1) << 5) | ((i15 >> 2) << 3) | ((t & 1) << 2) | (i15 & 3);
        half8 vv = *(half8*)&Lw[m * 72 + kk * 32 + ll4 * 8];
        *(half8*)(base + (size_t)(((t * 2 + kk) * 64 + ll4 * 16 + i15) * 8)) = vv;
      }
    } else {                                   // V fragment-swizzled
      _Float16* base = VF + (size_t)h * NT * HD + (size_t)kb * 4096;
#pragma unroll
      for (int i = 0; i < 8; ++i) {
        int t = i >> 1, kk = i & 1;
        int l15v = lane & 15, l4v = lane >> 4;
        half8 vv;
#pragma unroll
        for (int jj = 0; jj < 8; ++jj)
          vv[jj] = Lw[(kk * 32 + l4v * 8 + jj) * 72 + t * 16 + l15v];
        *(half8*)(base + (size_t)(((t * 2 + kk) * 64 + l4v * 16 + l15v) * 8)) = vv;
      }
    }
  }
}

// ---------------- GEMM (gemm2): C[M][Nn] = A[M][K] * Bt[Nn][K]^T ----------------
// 128x128 tile, BK=32, linear LDS, global_load_lds width-16, 2-phase dbuf,
// bijective XCD swizzle (nwg % 8 == 0). K % 64 == 0.
template <typename OutT>
__global__ __launch_bounds__(256) void gemm_bt(const _Float16* __restrict__ A,
                                               const _Float16* __restrict__ Bt,
                                               OutT* __restrict__ Cc,
                                               int M, int Nn, int K, int nbx) {
  __shared__ _Float16 As[2][128][32];
  __shared__ _Float16 Bs[2][128][32];
  const int tid = threadIdx.x;
  const int lane = tid & 63, w = tid >> 6;
  const int l15 = lane & 15, l4 = lane >> 4;
  int nwg = gridDim.x, cpx = nwg >> 3;
  int wg = (blockIdx.x & 7) * cpx + (blockIdx.x >> 3);
  const int m0 = (wg % nbx) * 128, n0 = (wg / nbx) * 128;
  const int wr = w >> 1, wc = w & 1;
  const int rb = w * 32;
  const int rl = lane >> 2;
  const int cb = (lane & 3) * 8;
  f32x4 acc[4][4] = {};
  auto stage = [&](int k0, int buf) {
    GLOAD_LDS16(A  + (size_t)(m0 + rb + rl) * K + k0 + cb,      &As[buf][rb][0]);
    GLOAD_LDS16(A  + (size_t)(m0 + rb + 16 + rl) * K + k0 + cb, &As[buf][rb + 16][0]);
    GLOAD_LDS16(Bt + (size_t)(n0 + rb + rl) * K + k0 + cb,      &Bs[buf][rb][0]);
    GLOAD_LDS16(Bt + (size_t)(n0 + rb + 16 + rl) * K + k0 + cb, &Bs[buf][rb + 16][0]);
  };
  auto compute = [&](int buf) {
    half8 af[4], bf[4];
#pragma unroll
    for (int mt = 0; mt < 4; ++mt) af[mt] = *(half8*)&As[buf][wr * 64 + mt * 16 + l15][l4 * 8];
#pragma unroll
    for (int nt = 0; nt < 4; ++nt) bf[nt] = *(half8*)&Bs[buf][wc * 64 + nt * 16 + l15][l4 * 8];
#pragma unroll
    for (int mt = 0; mt < 4; ++mt)
#pragma unroll
      for (int nt = 0; nt < 4; ++nt)
        acc[mt][nt] = __builtin_amdgcn_mfma_f32_16x16x32_f16(af[mt], bf[nt], acc[mt][nt], 0, 0, 0);
  };
  stage(0, 0);
  __syncthreads();
  for (int k0 = 0; k0 < K; k0 += 64) {
    stage(k0 + 32, 1);
    compute(0);
    __syncthreads();
    if (k0 + 64 < K) stage(k0 + 64, 0);
    compute(1);
    __syncthreads();
  }
#pragma unroll
  for (int mt = 0; mt < 4; ++mt)
#pragma unroll
    for (int nt = 0; nt < 4; ++nt)
#pragma unroll
      for (int r = 0; r < 4; ++r) {
        int row = m0 + wr * 64 + mt * 16 + l4 * 4 + r;
        int col = n0 + wc * 64 + nt * 16 + l15;
        Cc[(size_t)row * Nn + col] = (OutT)acc[mt][nt][r];
      }
}

// ---------------- flash attention: single-buffer gload_lds (r13-exact, 81.7us) ----------------
__global__ __launch_bounds__(256, 2) void attn_kernel(const _Float16* __restrict__ Qh,
                                                      const _Float16* __restrict__ KF,
                                                      const _Float16* __restrict__ VF,
                                                      _Float16* __restrict__ Oh) {
  __shared__ _Float16 KB[4096];
  __shared__ _Float16 VB[4096];
  const int tid = threadIdx.x, lane = tid & 63, w = tid >> 6;
  const int l15 = lane & 15, l4 = lane >> 4;
  int bid = blockIdx.x;
  int s = bid >> 3;
  int h = (bid & 7) * 2 + (s >> 5);
  int n0 = (s & 31) * 128;
  half8 qf[2][2];
#pragma unroll
  for (int qb = 0; qb < 2; ++qb)
#pragma unroll
    for (int kk = 0; kk < 2; ++kk)
      qf[qb][kk] = *(const half8*)(Qh + ((size_t)h * NT + n0 + w * 32 + qb * 16 + l15) * HD + kk * 32 + l4 * 8);
  f32x4 acc[2][4] = {};
  f32x4 acc5[2] = {};
  half8 of1 = {};
  if (l15 == 0) {
#pragma unroll
    for (int jq = 0; jq < 8; ++jq) of1[jq] = (_Float16)1.0f;
  }
  const _Float16* KFh = KF + (size_t)h * NT * HD + w * 512 + lane * 8;
  const _Float16* VFh = VF + (size_t)h * NT * HD + w * 512 + lane * 8;
  union U { half8 v; half2 p[4]; };
  for (int kb = 0; kb < 64; ++kb) {
    __syncthreads();
    {
      size_t g0 = (size_t)kb * 4096;
      GLOAD_LDS16(KFh + g0,        &KB[w * 512]);
      GLOAD_LDS16(KFh + g0 + 2048, &KB[2048 + w * 512]);
      GLOAD_LDS16(VFh + g0,        &VB[w * 512]);
      GLOAD_LDS16(VFh + g0 + 2048, &VB[2048 + w * 512]);
    }
    __syncthreads();
    f32x4 sv[2][4] = {};
    __builtin_amdgcn_s_setprio(1);
#pragma unroll
    for (int t = 0; t < 4; ++t)
#pragma unroll
      for (int kk = 0; kk < 2; ++kk) {
        half8 kf = *(half8*)&KB[(t * 2 + kk) * 512 + lane * 8];
        sv[0][t] = __builtin_amdgcn_mfma_f32_16x16x32_f16(kf, qf[0][kk], sv[0][t], 0, 0, 0);
        sv[1][t] = __builtin_amdgcn_mfma_f32_16x16x32_f16(kf, qf[1][kk], sv[1][t], 0, 0, 0);
      }
    __builtin_amdgcn_s_setprio(0);
    U u[2][2];
#pragma unroll
    for (int qb = 0; qb < 2; ++qb) {
      float e[4][4];
#pragma unroll
      for (int t = 0; t < 4; ++t)
#pragma unroll
        for (int r = 0; r < 4; ++r) e[t][r] = EXP2(sv[qb][t][r]);
      u[qb][0].p[0] = pk_f16(e[0][0], e[0][1]); u[qb][0].p[1] = pk_f16(e[0][2], e[0][3]);
      u[qb][0].p[2] = pk_f16(e[1][0], e[1][1]); u[qb][0].p[3] = pk_f16(e[1][2], e[1][3]);
      u[qb][1].p[0] = pk_f16(e[2][0], e[2][1]); u[qb][1].p[1] = pk_f16(e[2][2], e[2][3]);
      u[qb][1].p[2] = pk_f16(e[3][0], e[3][1]); u[qb][1].p[3] = pk_f16(e[3][2], e[3][3]);
    }
    __builtin_amdgcn_s_setprio(1);
#pragma unroll
    for (int t = 0; t < 4; ++t)
#pragma unroll
      for (int kk = 0; kk < 2; ++kk) {
        half8 vf = *(half8*)&VB[(t * 2 + kk) * 512 + lane * 8];
        acc[0][t] = __builtin_amdgcn_mfma_f32_16x16x32_f16(u[0][kk].v, vf, acc[0][t], 0, 0, 0);
        acc[1][t] = __builtin_amdgcn_mfma_f32_16x16x32_f16(u[1][kk].v, vf, acc[1][t], 0, 0, 0);
      }
    acc5[0] = __builtin_amdgcn_mfma_f32_16x16x32_f16(u[0][0].v, of1, acc5[0], 0, 0, 0);
    acc5[0] = __builtin_amdgcn_mfma_f32_16x16x32_f16(u[0][1].v, of1, acc5[0], 0, 0, 0);
    acc5[1] = __builtin_amdgcn_mfma_f32_16x16x32_f16(u[1][0].v, of1, acc5[1], 0, 0, 0);
    acc5[1] = __builtin_amdgcn_mfma_f32_16x16x32_f16(u[1][1].v, of1, acc5[1], 0, 0, 0);
    __builtin_amdgcn_s_setprio(0);
  }
#pragma unroll
  for (int qb = 0; qb < 2; ++qb) {
    float linv[4];
#pragma unroll
    for (int r = 0; r < 4; ++r) linv[r] = 1.0f / __shfl(acc5[qb][r], lane & 48);
#pragma unroll
    for (int t = 0; t < 4; ++t)
#pragma unroll
      for (int r = 0; r < 4; ++r) {
        int row = n0 + w * 32 + qb * 16 + l4 * 4 + r;
        Oh[(size_t)row * CH + h * HD + t * 16 + l15] = (_Float16)(acc[qb][t][r] * linv[r]);
      }
  }
}

extern "C" void kernel_launch(void* const* d_in, const int* in_sizes, int n_in,
                              void* d_out, int out_size, void* d_ws, size_t ws_size,
                              hipStream_t stream) {
  const float* x      = (const float*)d_in[0];
  const int*   coords = (const int*)d_in[1];
  const float* w_qkv  = (const float*)d_in[2];
  const float* w_out  = (const float*)d_in[3];
  const float* gq     = (const float*)d_in[4];
  const float* gk     = (const float*)d_in[5];
  float* out = (float*)d_out;

  char* ws = (char*)d_ws;
  size_t off = 0;
  auto alloc = [&](size_t bytes) { char* p = ws + off; off += bytes; return p; };
  _Float16* xh   = (_Float16*)alloc((size_t)NT * CH * 2);  // x f16
  _Float16* wqh  = (_Float16*)alloc((size_t)C3 * CH * 2);  // w_qkv f16
  _Float16* woh  = (_Float16*)alloc((size_t)CH * CH * 2);  // w_out f16
  float2*   csn  = (float2*)alloc((size_t)NT * 32 * 8);    // rope cos/sin table
  _Float16* Qh   = (_Float16*)alloc((size_t)NT * CH * 2);  // [H][N][64], pre-scaled
  _Float16* KFh  = (_Float16*)alloc((size_t)NT * CH * 2);  // frag-swizzled K
  _Float16* VFh  = (_Float16*)alloc((size_t)NT * CH * 2);  // frag-swizzled V
  _Float16* Oh   = (_Float16*)alloc((size_t)NT * CH * 2);  // attn out [N][C]
  if (off > ws_size) return;  // workspace too small: fail cleanly

  int na4 = NT * CH / 4, nb4 = C3 * CH / 4, nc4 = CH * CH / 4;
  cvt3_kernel<<<(na4 + nb4 + nc4) / 256, 256, 0, stream>>>(x, na4, w_qkv, nb4, w_out, nc4,
                                                           xh, wqh, woh);
  rope_tab_kernel<<<NT * 32 / 256, 256, 0, stream>>>(coords, csn);
  gemm_qkv<<<(NT / 256) * (C3 / 256), 512, 0, stream>>>(xh, wqh, csn, gq, gk, Qh, KFh, VFh);
  attn_kernel<<<NH * (NT / 128), 256, 0, stream>>>(Qh, KFh, VFh, Oh);
  gemm_bt<float><<<(NT / 128) * (CH / 128), 256, 0, stream>>>(Oh, woh, out, NT, CH, CH, NT / 128);
}

// Round 18
// 153.693 us; speedup vs baseline: 1.2805x; 1.0027x over previous
//
#include <hip/hip_runtime.h>
#include <hip/hip_bf16.h>

typedef _Float16 half8 __attribute__((ext_vector_type(8)));
typedef _Float16 half4v __attribute__((ext_vector_type(4)));
typedef _Float16 half2 __attribute__((ext_vector_type(2)));
typedef float f32x4 __attribute__((ext_vector_type(4)));

constexpr int NT = 4096;   // tokens
constexpr int CH = 1024;   // channels
constexpr int NH = 16;     // heads
constexpr int HD = 64;     // head dim
constexpr int C3 = 3072;   // 3*CH

#if __has_builtin(__builtin_amdgcn_exp2f)
#define EXP2(x) __builtin_amdgcn_exp2f(x)
#else
#define EXP2(x) exp2f(x)
#endif

#define GLOAD_LDS16(gp, lp) __builtin_amdgcn_global_load_lds( \
    (const __attribute__((address_space(1))) void*)(gp),      \
    (__attribute__((address_space(3))) void*)(lp), 16, 0, 0)

// counted waits (T4): loads stay in flight across raw barriers
#define WAITCNT4 do { asm volatile("s_waitcnt vmcnt(4)" ::: "memory"); \
                      __builtin_amdgcn_sched_barrier(0); } while (0)
#define WAITCNT0 do { asm volatile("s_waitcnt vmcnt(0)" ::: "memory"); \
                      __builtin_amdgcn_sched_barrier(0); } while (0)

static __device__ inline half2 pk_f16(float a, float b) {
  auto r = __builtin_amdgcn_cvt_pkrtz(a, b);   // v_cvt_pkrtz_f16_f32
  return *(half2*)&r;
}

// ---------------- fused f32 -> f16 convert (x, w_qkv, w_out in one launch) ----------------
__global__ __launch_bounds__(256) void cvt3_kernel(const float* __restrict__ a, int na4,
                                                   const float* __restrict__ b, int nb4,
                                                   const float* __restrict__ c, int nc4,
                                                   _Float16* __restrict__ oa,
                                                   _Float16* __restrict__ ob,
                                                   _Float16* __restrict__ oc) {
  int i = blockIdx.x * 256 + threadIdx.x;
  const float* src; _Float16* dst; int j = i;
  if (i < na4) { src = a; dst = oa; }
  else if (i < na4 + nb4) { src = b; dst = ob; j = i - na4; }
  else if (i < na4 + nb4 + nc4) { src = c; dst = oc; j = i - na4 - nb4; }
  else return;
  float4 v = ((const float4*)src)[j];
  half4v h;
  h[0] = (_Float16)v.x; h[1] = (_Float16)v.y; h[2] = (_Float16)v.z; h[3] = (_Float16)v.w;
  ((half4v*)dst)[j] = h;
}

// ---------------- RoPE cos/sin table: csn[n*32 + j] = {cos, sin}(ang(n,j)) ----------------
__global__ __launch_bounds__(256) void rope_tab_kernel(const int* __restrict__ coords,
                                                       float2* __restrict__ csn) {
  int idx = blockIdx.x * 256 + threadIdx.x;   // NT*32 exact
  int n = idx >> 5, j = idx & 31;
  float ang = (float)coords[n * 5 + 1 + (j >> 3)] * __expf(-(float)(j & 7) * 0.14391157f);
  csn[idx] = make_float2(cosf(ang), sinf(ang));
}

// ---------------- fused QKV GEMM (256x256) + RMSNorm + RoPE + K/V frag-swizzle ----------------
// r17 structure + counted-vmcnt schedule: raw s_barrier (no implicit drain),
// depth-2 prefetch, s_waitcnt vmcnt(4) per tile (never 0 in the loop).
// At 1 block/CU there is no co-resident block to hide a vmcnt(0) drain --
// counted waits keep the next tile's 4 loads in flight across both barriers.
__global__ __launch_bounds__(512, 2) void gemm_qkv(const _Float16* __restrict__ A,
                                                   const _Float16* __restrict__ Bt,
                                                   const float2* __restrict__ csn,
                                                   const float* __restrict__ gq,
                                                   const float* __restrict__ gk,
                                                   _Float16* __restrict__ Qh,
                                                   _Float16* __restrict__ KF,
                                                   _Float16* __restrict__ VF) {
  __shared__ __align__(16) char smem[73728];          // GEMM: 64KB; epilogue: 8x9216
  auto As = (_Float16(*)[256][32])smem;               // [2][256][32] = 32KB
  auto Bs = (_Float16(*)[256][32])(smem + 32768);     // [2][256][32] = 32KB
  const int K = CH;
  const int tid = threadIdx.x;
  const int lane = tid & 63, w = tid >> 6;
  const int l15 = lane & 15, l4 = lane >> 4;
  int nwg = gridDim.x, cpx = nwg >> 3;
  int wg = (blockIdx.x & 7) * cpx + (blockIdx.x >> 3);
  const int nbx = NT / 256;                           // 16
  const int bm = wg % nbx, bn = wg / nbx;
  const int m0 = bm * 256, n0 = bn * 256;
  const int wr = w >> 2, wc = w & 3;                  // 2 x 4 waves
  const int rb = w * 32;           // wave's 32-row staging band (8 waves x 32 = 256)
  const int rl = lane >> 2;        // row within 16-row chunk (4 lanes/row)
  const int cb = (lane & 3) * 8;   // f16 col of this lane's 16B
  f32x4 acc[8][4] = {};
  auto stage = [&](int k0, int buf) {   // exactly 4 gload_lds per thread
    GLOAD_LDS16(A  + (size_t)(m0 + rb + rl) * K + k0 + cb,      &As[buf][rb][0]);
    GLOAD_LDS16(A  + (size_t)(m0 + rb + 16 + rl) * K + k0 + cb, &As[buf][rb + 16][0]);
    GLOAD_LDS16(Bt + (size_t)(n0 + rb + rl) * K + k0 + cb,      &Bs[buf][rb][0]);
    GLOAD_LDS16(Bt + (size_t)(n0 + rb + 16 + rl) * K + k0 + cb, &Bs[buf][rb + 16][0]);
  };
  auto compute = [&](int buf) {
    half8 af[8], bf[4];
#pragma unroll
    for (int mt = 0; mt < 8; ++mt) af[mt] = *(half8*)&As[buf][wr * 128 + mt * 16 + l15][l4 * 8];
#pragma unroll
    for (int nt = 0; nt < 4; ++nt) bf[nt] = *(half8*)&Bs[buf][wc * 64 + nt * 16 + l15][l4 * 8];
    __builtin_amdgcn_s_setprio(1);
#pragma unroll
    for (int mt = 0; mt < 8; ++mt)
#pragma unroll
      for (int nt = 0; nt < 4; ++nt)
        acc[mt][nt] = __builtin_amdgcn_mfma_f32_16x16x32_f16(af[mt], bf[nt], acc[mt][nt], 0, 0, 0);
    __builtin_amdgcn_s_setprio(0);
  };
  stage(0, 0);
  stage(32, 1);
  for (int k0 = 0; k0 < K - 32; k0 += 32) {
    int buf = (k0 >> 5) & 1;
    WAITCNT4;                          // own stage(k0) done; stage(k0+32) stays in flight
    __builtin_amdgcn_s_barrier();      // all waves' stage(k0) done; prior buf readers done
    compute(buf);
    __builtin_amdgcn_s_barrier();      // all reads of buf done -> safe to re-stage
    if (k0 + 64 < K) stage(k0 + 64, buf);
  }
  WAITCNT0;                            // last tile: drain
  __builtin_amdgcn_s_barrier();
  compute(((K - 32) >> 5) & 1);
  __builtin_amdgcn_s_barrier();        // seal LDS reads before epilogue reuses smem
  // ---- fused epilogue (per-wave private LDS region) ----
  const int gc0 = n0 + wc * 64;
  const int sec = gc0 >> 10;                 // 0=q, 1=k, 2=v
  const int h   = (gc0 & 1023) >> 6;
  _Float16* Lw = (_Float16*)(smem + w * 9216);   // [64][72] f16
  float gmm[4];
  if (sec < 2) {
    const float* gm = (sec == 0) ? gq : gk;
#pragma unroll
    for (int nt = 0; nt < 4; ++nt) gmm[nt] = gm[h * 64 + nt * 16 + l15];
  }
  const float qsc = (sec == 0) ? 0.18033688f : 1.0f;   // 0.125*log2(e) for Q
#pragma unroll
  for (int half = 0; half < 2; ++half) {
    const int K0 = m0 + wr * 128 + half * 64;  // token base of this 64-row half
    if (sec < 2) {                             // ---- Q/K: RMSNorm + RoPE ----
#pragma unroll
      for (int mt = 0; mt < 4; ++mt)
#pragma unroll
        for (int r = 0; r < 4; ++r) {
          float ss = 0.f;
#pragma unroll
          for (int nt = 0; nt < 4; ++nt)
            ss += acc[half * 4 + mt][nt][r] * acc[half * 4 + mt][nt][r];
          ss += __shfl_xor(ss, 1); ss += __shfl_xor(ss, 2);
          ss += __shfl_xor(ss, 4); ss += __shfl_xor(ss, 8);
          float sc = 8.0f / fmaxf(sqrtf(ss), 1e-12f);
          int row = mt * 16 + l4 * 4 + r;      // local row in this half
          int n = K0 + row;
#pragma unroll
          for (int nt = 0; nt < 4; ++nt) {
            float v = acc[half * 4 + mt][nt][r] * sc * gmm[nt];
            float2 cz = csn[n * 32 + nt * 8 + (l15 >> 1)];
            float p = __shfl_xor(v, 1);
            float o = ((l15 & 1) == 0) ? (v * cz.x - p * cz.y) : (p * cz.y + v * cz.x);
            Lw[row * 72 + nt * 16 + l15] = (_Float16)(o * qsc);
          }
        }
    } else {                                   // ---- V: passthrough ----
#pragma unroll
      for (int mt = 0; mt < 4; ++mt)
#pragma unroll
        for (int r = 0; r < 4; ++r) {
          int row = mt * 16 + l4 * 4 + r;
#pragma unroll
          for (int nt = 0; nt < 4; ++nt)
            Lw[row * 72 + nt * 16 + l15] = (_Float16)acc[half * 4 + mt][nt][r];
        }
    }
    // within-wave LDS write->read: lockstep program order, no barrier needed
    const int kb = K0 >> 6;
    if (sec == 0) {                            // Q row-major: [h][NT][64]
#pragma unroll
      for (int i = 0; i < 8; ++i) {
        int row = i * 8 + (lane >> 3), col = (lane & 7) * 8;
        half8 vv = *(half8*)&Lw[row * 72 + col];
        *(half8*)(Qh + ((size_t)h * NT + K0 + row) * 64 + col) = vv;
      }
    } else if (sec == 1) {                     // K fragment-swizzled
      _Float16* base = KF + (size_t)h * NT * HD + (size_t)kb * 4096;
#pragma unroll
      for (int i = 0; i < 8; ++i) {
        int t = i >> 1, kk = i & 1;
        int i15 = lane & 15, ll4 = lane >> 4;
        // invert: t=2*(m>>5)+((m>>2)&1); i15=4*((m>>3)&3)+(m&3)
        int m = ((t >> 1) << 5) | ((i15 >> 2) << 3) | ((t & 1) << 2) | (i15 & 3);
        half8 vv = *(half8*)&Lw[m * 72 + kk * 32 + ll4 * 8];
        *(half8*)(base + (size_t)(((t * 2 + kk) * 64 + ll4 * 16 + i15) * 8)) = vv;
      }
    } else {                                   // V fragment-swizzled
      _Float16* base = VF + (size_t)h * NT * HD + (size_t)kb * 4096;
#pragma unroll
      for (int i = 0; i < 8; ++i) {
        int t = i >> 1, kk = i & 1;
        int l15v = lane & 15, l4v = lane >> 4;
        half8 vv;
#pragma unroll
        for (int jj = 0; jj < 8; ++jj)
          vv[jj] = Lw[(kk * 32 + l4v * 8 + jj) * 72 + t * 16 + l15v];
        *(half8*)(base + (size_t)(((t * 2 + kk) * 64 + l4v * 16 + l15v) * 8)) = vv;
      }
    }
  }
}

// ---------------- GEMM (gemm2): C[M][Nn] = A[M][K] * Bt[Nn][K]^T ----------------
// 128x128 tile, BK=32, linear LDS, gload_lds, counted-vmcnt 2-phase,
// bijective XCD swizzle (nwg % 8 == 0). K % 64 == 0.
template <typename OutT>
__global__ __launch_bounds__(256) void gemm_bt(const _Float16* __restrict__ A,
                                               const _Float16* __restrict__ Bt,
                                               OutT* __restrict__ Cc,
                                               int M, int Nn, int K, int nbx) {
  __shared__ _Float16 As[2][128][32];
  __shared__ _Float16 Bs[2][128][32];
  const int tid = threadIdx.x;
  const int lane = tid & 63, w = tid >> 6;
  const int l15 = lane & 15, l4 = lane >> 4;
  int nwg = gridDim.x, cpx = nwg >> 3;
  int wg = (blockIdx.x & 7) * cpx + (blockIdx.x >> 3);
  const int m0 = (wg % nbx) * 128, n0 = (wg / nbx) * 128;
  const int wr = w >> 1, wc = w & 1;
  const int rb = w * 32;
  const int rl = lane >> 2;
  const int cb = (lane & 3) * 8;
  f32x4 acc[4][4] = {};
  auto stage = [&](int k0, int buf) {   // exactly 4 gload_lds per thread
    GLOAD_LDS16(A  + (size_t)(m0 + rb + rl) * K + k0 + cb,      &As[buf][rb][0]);
    GLOAD_LDS16(A  + (size_t)(m0 + rb + 16 + rl) * K + k0 + cb, &As[buf][rb + 16][0]);
    GLOAD_LDS16(Bt + (size_t)(n0 + rb + rl) * K + k0 + cb,      &Bs[buf][rb][0]);
    GLOAD_LDS16(Bt + (size_t)(n0 + rb + 16 + rl) * K + k0 + cb, &Bs[buf][rb + 16][0]);
  };
  auto compute = [&](int buf) {
    half8 af[4], bf[4];
#pragma unroll
    for (int mt = 0; mt < 4; ++mt) af[mt] = *(half8*)&As[buf][wr * 64 + mt * 16 + l15][l4 * 8];
#pragma unroll
    for (int nt = 0; nt < 4; ++nt) bf[nt] = *(half8*)&Bs[buf][wc * 64 + nt * 16 + l15][l4 * 8];
    __builtin_amdgcn_s_setprio(1);
#pragma unroll
    for (int mt = 0; mt < 4; ++mt)
#pragma unroll
      for (int nt = 0; nt < 4; ++nt)
        acc[mt][nt] = __builtin_amdgcn_mfma_f32_16x16x32_f16(af[mt], bf[nt], acc[mt][nt], 0, 0, 0);
    __builtin_amdgcn_s_setprio(0);
  };
  stage(0, 0);
  stage(32, 1);
  for (int k0 = 0; k0 < K - 32; k0 += 32) {
    int buf = (k0 >> 5) & 1;
    WAITCNT4;
    __builtin_amdgcn_s_barrier();
    compute(buf);
    __builtin_amdgcn_s_barrier();
    if (k0 + 64 < K) stage(k0 + 64, buf);
  }
  WAITCNT0;
  __builtin_amdgcn_s_barrier();
  compute(((K - 32) >> 5) & 1);
#pragma unroll
  for (int mt = 0; mt < 4; ++mt)
#pragma unroll
    for (int nt = 0; nt < 4; ++nt)
#pragma unroll
      for (int r = 0; r < 4; ++r) {
        int row = m0 + wr * 64 + mt * 16 + l4 * 4 + r;
        int col = n0 + wc * 64 + nt * 16 + l15;
        Cc[(size_t)row * Nn + col] = (OutT)acc[mt][nt][r];
      }
}

// ---------------- flash attention: single-buffer gload_lds (r13-exact, 81.7us) ----------------
__global__ __launch_bounds__(256, 2) void attn_kernel(const _Float16* __restrict__ Qh,
                                                      const _Float16* __restrict__ KF,
                                                      const _Float16* __restrict__ VF,
                                                      _Float16* __restrict__ Oh) {
  __shared__ _Float16 KB[4096];
  __shared__ _Float16 VB[4096];
  const int tid = threadIdx.x, lane = tid & 63, w = tid >> 6;
  const int l15 = lane & 15, l4 = lane >> 4;
  int bid = blockIdx.x;
  int s = bid >> 3;
  int h = (bid & 7) * 2 + (s >> 5);
  int n0 = (s & 31) * 128;
  half8 qf[2][2];
#pragma unroll
  for (int qb = 0; qb < 2; ++qb)
#pragma unroll
    for (int kk = 0; kk < 2; ++kk)
      qf[qb][kk] = *(const half8*)(Qh + ((size_t)h * NT + n0 + w * 32 + qb * 16 + l15) * HD + kk * 32 + l4 * 8);
  f32x4 acc[2][4] = {};
  f32x4 acc5[2] = {};
  half8 of1 = {};
  if (l15 == 0) {
#pragma unroll
    for (int jq = 0; jq < 8; ++jq) of1[jq] = (_Float16)1.0f;
  }
  const _Float16* KFh = KF + (size_t)h * NT * HD + w * 512 + lane * 8;
  const _Float16* VFh = VF + (size_t)h * NT * HD + w * 512 + lane * 8;
  union U { half8 v; half2 p[4]; };
  for (int kb = 0; kb < 64; ++kb) {
    __syncthreads();
    {
      size_t g0 = (size_t)kb * 4096;
      GLOAD_LDS16(KFh + g0,        &KB[w * 512]);
      GLOAD_LDS16(KFh + g0 + 2048, &KB[2048 + w * 512]);
      GLOAD_LDS16(VFh + g0,        &VB[w * 512]);
      GLOAD_LDS16(VFh + g0 + 2048, &VB[2048 + w * 512]);
    }
    __syncthreads();
    f32x4 sv[2][4] = {};
    __builtin_amdgcn_s_setprio(1);
#pragma unroll
    for (int t = 0; t < 4; ++t)
#pragma unroll
      for (int kk = 0; kk < 2; ++kk) {
        half8 kf = *(half8*)&KB[(t * 2 + kk) * 512 + lane * 8];
        sv[0][t] = __builtin_amdgcn_mfma_f32_16x16x32_f16(kf, qf[0][kk], sv[0][t], 0, 0, 0);
        sv[1][t] = __builtin_amdgcn_mfma_f32_16x16x32_f16(kf, qf[1][kk], sv[1][t], 0, 0, 0);
      }
    __builtin_amdgcn_s_setprio(0);
    U u[2][2];
#pragma unroll
    for (int qb = 0; qb < 2; ++qb) {
      float e[4][4];
#pragma unroll
      for (int t = 0; t < 4; ++t)
#pragma unroll
        for (int r = 0; r < 4; ++r) e[t][r] = EXP2(sv[qb][t][r]);
      u[qb][0].p[0] = pk_f16(e[0][0], e[0][1]); u[qb][0].p[1] = pk_f16(e[0][2], e[0][3]);
      u[qb][0].p[2] = pk_f16(e[1][0], e[1][1]); u[qb][0].p[3] = pk_f16(e[1][2], e[1][3]);
      u[qb][1].p[0] = pk_f16(e[2][0], e[2][1]); u[qb][1].p[1] = pk_f16(e[2][2], e[2][3]);
      u[qb][1].p[2] = pk_f16(e[3][0], e[3][1]); u[qb][1].p[3] = pk_f16(e[3][2], e[3][3]);
    }
    __builtin_amdgcn_s_setprio(1);
#pragma unroll
    for (int t = 0; t < 4; ++t)
#pragma unroll
      for (int kk = 0; kk < 2; ++kk) {
        half8 vf = *(half8*)&VB[(t * 2 + kk) * 512 + lane * 8];
        acc[0][t] = __builtin_amdgcn_mfma_f32_16x16x32_f16(u[0][kk].v, vf, acc[0][t], 0, 0, 0);
        acc[1][t] = __builtin_amdgcn_mfma_f32_16x16x32_f16(u[1][kk].v, vf, acc[1][t], 0, 0, 0);
      }
    acc5[0] = __builtin_amdgcn_mfma_f32_16x16x32_f16(u[0][0].v, of1, acc5[0], 0, 0, 0);
    acc5[0] = __builtin_amdgcn_mfma_f32_16x16x32_f16(u[0][1].v, of1, acc5[0], 0, 0, 0);
    acc5[1] = __builtin_amdgcn_mfma_f32_16x16x32_f16(u[1][0].v, of1, acc5[1], 0, 0, 0);
    acc5[1] = __builtin_amdgcn_mfma_f32_16x16x32_f16(u[1][1].v, of1, acc5[1], 0, 0, 0);
    __builtin_amdgcn_s_setprio(0);
  }
#pragma unroll
  for (int qb = 0; qb < 2; ++qb) {
    float linv[4];
#pragma unroll
    for (int r = 0; r < 4; ++r) linv[r] = 1.0f / __shfl(acc5[qb][r], lane & 48);
#pragma unroll
    for (int t = 0; t < 4; ++t)
#pragma unroll
      for (int r = 0; r < 4; ++r) {
        int row = n0 + w * 32 + qb * 16 + l4 * 4 + r;
        Oh[(size_t)row * CH + h * HD + t * 16 + l15] = (_Float16)(acc[qb][t][r] * linv[r]);
      }
  }
}

extern "C" void kernel_launch(void* const* d_in, const int* in_sizes, int n_in,
                              void* d_out, int out_size, void* d_ws, size_t ws_size,
                              hipStream_t stream) {
  const float* x      = (const float*)d_in[0];
  const int*   coords = (const int*)d_in[1];
  const float* w_qkv  = (const float*)d_in[2];
  const float* w_out  = (const float*)d_in[3];
  const float* gq     = (const float*)d_in[4];
  const float* gk     = (const float*)d_in[5];
  float* out = (float*)d_out;

  char* ws = (char*)d_ws;
  size_t off = 0;
  auto alloc = [&](size_t bytes) { char* p = ws + off; off += bytes; return p; };
  _Float16* xh   = (_Float16*)alloc((size_t)NT * CH * 2);  // x f16
  _Float16* wqh  = (_Float16*)alloc((size_t)C3 * CH * 2);  // w_qkv f16
  _Float16* woh  = (_Float16*)alloc((size_t)CH * CH * 2);  // w_out f16
  float2*   csn  = (float2*)alloc((size_t)NT * 32 * 8);    // rope cos/sin table
  _Float16* Qh   = (_Float16*)alloc((size_t)NT * CH * 2);  // [H][N][64], pre-scaled
  _Float16* KFh  = (_Float16*)alloc((size_t)NT * CH * 2);  // frag-swizzled K
  _Float16* VFh  = (_Float16*)alloc((size_t)NT * CH * 2);  // frag-swizzled V
  _Float16* Oh   = (_Float16*)alloc((size_t)NT * CH * 2);  // attn out [N][C]
  if (off > ws_size) return;  // workspace too small: fail cleanly

  int na4 = NT * CH / 4, nb4 = C3 * CH / 4, nc4 = CH * CH / 4;
  cvt3_kernel<<<(na4 + nb4 + nc4) / 256, 256, 0, stream>>>(x, na4, w_qkv, nb4, w_out, nc4,
                                                           xh, wqh, woh);
  rope_tab_kernel<<<NT * 32 / 256, 256, 0, stream>>>(coords, csn);
  gemm_qkv<<<(NT / 256) * (C3 / 256), 512, 0, stream>>>(xh, wqh, csn, gq, gk, Qh, KFh, VFh);
  attn_kernel<<<NH * (NT / 128), 256, 0, stream>>>(Qh, KFh, VFh, Oh);
  gemm_bt<float><<<(NT / 128) * (CH / 128), 256, 0, stream>>>(Oh, woh, out, NT, CH, CH, NT / 128);
}